// Round 10
// baseline (123.275 us; speedup 1.0000x reference)
//
#include <hip/hip_runtime.h>
#include <hip/hip_bf16.h>
#include <stdint.h>

#define DEV static __device__ __forceinline__

typedef __attribute__((ext_vector_type(8))) __bf16 bf16x8;
typedef __attribute__((ext_vector_type(4))) __bf16 bf16x4;
typedef __attribute__((ext_vector_type(4))) float f32x4;
typedef __attribute__((ext_vector_type(16))) float f32x16;

// B=2, T=2048, C=1024, NH=16, HS=64
#define BB 2
#define TT 2048
#define CC 1024
#define NHH 16
#define HSS 64
#define BT 4096
#define N3 3072

DEV unsigned short f2bf(float f) {
  union { float f; uint32_t u; } v; v.f = f;
  uint32_t r = v.u + 0x7FFFu + ((v.u >> 16) & 1u);
  return (unsigned short)(r >> 16);
}

typedef const __attribute__((address_space(1))) unsigned int* gas_t;
typedef __attribute__((address_space(3))) unsigned int* las_t;

DEV void glds16(const void* g, void* l) {
  __builtin_amdgcn_global_load_lds((gas_t)g, (las_t)l, 16, 0, 0);
}

DEV f32x4 mfma16(bf16x8 a, bf16x8 b, f32x4 c) {
  return __builtin_amdgcn_mfma_f32_16x16x32_bf16(a, b, c, 0, 0, 0);
}
DEV f32x16 mfma32(bf16x8 a, bf16x8 b, f32x16 c) {
  return __builtin_amdgcn_mfma_f32_32x32x16_bf16(a, b, c, 0, 0, 0);
}

DEV bf16x8 ld8(const unsigned short* p) { return *(const bf16x8*)p; }

DEV f32x16 z16() {
  f32x16 v;
#pragma unroll
  for (int i = 0; i < 16; i++) v[i] = 0.f;
  return v;
}

// ---------- fp32 -> bf16 convert (vectorized) ----------
__global__ void k_conv(const float* __restrict__ in, unsigned short* __restrict__ out, int n4) {
  int i = blockIdx.x * blockDim.x + threadIdx.x;
  int stride = gridDim.x * blockDim.x;
  for (; i < n4; i += stride) {
    float4 v = ((const float4*)in)[i];
    ushort4 o;
    o.x = f2bf(v.x); o.y = f2bf(v.y); o.z = f2bf(v.z); o.w = f2bf(v.w);
    ((ushort4*)out)[i] = o;
  }
}

// ---------- transpose+convert: in [K][N] f32 -> out [N][K] bf16 ----------
__global__ void k_transp(const float* __restrict__ in, unsigned short* __restrict__ out,
                         int K, int N) {
  __shared__ float tile[32][33];
  int n0 = blockIdx.x * 32, k0 = blockIdx.y * 32;
  int tx = threadIdx.x, ty = threadIdx.y;  // (32,8)
  for (int r = ty; r < 32; r += 8)
    tile[r][tx] = in[(size_t)(k0 + r) * N + n0 + tx];
  __syncthreads();
  for (int r = ty; r < 32; r += 8)
    out[(size_t)(n0 + r) * K + k0 + tx] = f2bf(tile[tx][r]);
}

// ---------- GEMM: A[M][K] bf16, Bt[N][K] bf16, bias f32[N] ----------
// 128x128 tile, BK=32, 4 waves, double-buffered LDS + counted vmcnt (T3-min
// 2-phase), XCD-chunked bijective block swizzle (requires gridDim.x % 8 == 0).
template <int OUT_BF16>
__global__ __launch_bounds__(256) void k_gemm(const unsigned short* __restrict__ A,
                                              const unsigned short* __restrict__ Bt,
                                              const float* __restrict__ bias,
                                              void* __restrict__ Cout,
                                              int N, int K, int gx) {
  __shared__ __align__(16) unsigned short As[2][128 * 32];
  __shared__ __align__(16) unsigned short Bs[2][128 * 32];
  const int t = threadIdx.x;
  const int wave = t >> 6, l = t & 63, lr = l & 15, lg = l >> 4;
  const int cpx = gridDim.x >> 3;
  const int sw = ((int)blockIdx.x & 7) * cpx + ((int)blockIdx.x >> 3);
  const int m0 = (sw / gx) * 128, n0 = (sw % gx) * 128;
  const int wm = wave >> 1, wn = wave & 1;

  f32x4 acc[4][4] = {};

  const unsigned short* gA = A + (size_t)(m0 + (t >> 2)) * K + (t & 3) * 8;
  const unsigned short* gB = Bt + (size_t)(n0 + (t >> 2)) * K + (t & 3) * 8;
  const size_t rstep = (size_t)64 * K;

#define GSTAGE(buf_, k_)                                                  \
  do {                                                                    \
    glds16(gA + (k_), (char*)As[buf_] + wave * 1024);                     \
    glds16(gA + rstep + (k_), (char*)As[buf_] + 4096 + wave * 1024);      \
    glds16(gB + (k_), (char*)Bs[buf_] + wave * 1024);                     \
    glds16(gB + rstep + (k_), (char*)Bs[buf_] + 4096 + wave * 1024);      \
  } while (0)

  GSTAGE(0, 0);
  asm volatile("s_waitcnt vmcnt(0)" ::: "memory");
  __builtin_amdgcn_s_barrier();
  __builtin_amdgcn_sched_barrier(0);

  int cur = 0;
  for (int k0 = 0; k0 < K; k0 += 32) {
    if (k0 + 32 < K) GSTAGE(cur ^ 1, k0 + 32);
    __builtin_amdgcn_sched_barrier(0);
    bf16x8 av[4], bv[4];
#pragma unroll
    for (int i = 0; i < 4; i++) {
      av[i] = ld8(As[cur] + (wm * 64 + i * 16 + lr) * 32 + lg * 8);
      bv[i] = ld8(Bs[cur] + (wn * 64 + i * 16 + lr) * 32 + lg * 8);
    }
#pragma unroll
    for (int i = 0; i < 4; i++)
#pragma unroll
      for (int j = 0; j < 4; j++)
        acc[i][j] = mfma16(av[i], bv[j], acc[i][j]);
    if (k0 + 32 < K) asm volatile("s_waitcnt vmcnt(0)" ::: "memory");
    __builtin_amdgcn_s_barrier();
    __builtin_amdgcn_sched_barrier(0);
    cur ^= 1;
  }
#undef GSTAGE

#pragma unroll
  for (int j2 = 0; j2 < 4; j2++) {
    int col = n0 + wn * 64 + j2 * 16 + lr;
    float bv_ = bias[col];
#pragma unroll
    for (int i = 0; i < 4; i++) {
      int row = m0 + wm * 64 + i * 16 + lg * 4;
#pragma unroll
      for (int r = 0; r < 4; r++) {
        float v = acc[i][j2][r] + bv_;
        if (OUT_BF16)
          ((unsigned short*)Cout)[(size_t)(row + r) * N + col] = f2bf(v);
        else
          ((float*)Cout)[(size_t)(row + r) * N + col] = v;
      }
    }
  }
}

// ---------- per-head V transpose: qkv[b][t][2048+h*64+d] -> vt[bh][d][t] ----------
__global__ void k_vt(const unsigned short* __restrict__ qkv, unsigned short* __restrict__ vt) {
  __shared__ unsigned short tile[64][65];
  int bh = blockIdx.y, t0 = blockIdx.x * 64;
  int b = bh >> 4, h = bh & 15;
  int tx = threadIdx.x, ty = threadIdx.y;  // (64,4)
  const unsigned short* src = qkv + (size_t)(b * TT + t0) * N3 + 2 * CC + h * HSS;
  for (int r = ty; r < 64; r += 4)
    tile[r][tx] = src[(size_t)r * N3 + tx];
  __syncthreads();
  unsigned short* dst = vt + (size_t)bh * HSS * TT + t0;
  for (int r = ty; r < 64; r += 4)
    dst[(size_t)r * TT + tx] = tile[tx][r];
}

// ---------- flash attention: 512 blocks x 4 waves, 2 blocks/CU ----------
// Block = (bh, pp, qh): segment A = q-tile 15-pp rows [qh*64, qh*64+64), then
// segment B = q-tile pp same rows -> 17 macro-steps of 128 kv, uniform.
// Wave = (qsub 0/1, par 0/1): 32 q-rows x 64-kv parity half. Ring-2 K/V LDS
// (stage after barrier, vmcnt(0) at top), P-bounce in Ps, parity merge staged
// through the FREE K/V ring slot. LDS = 80 KiB exactly -> 2 blocks/CU.
__global__ __launch_bounds__(256) void k_attn(const unsigned short* __restrict__ qkv,
                                              const unsigned short* __restrict__ vt,
                                              unsigned short* __restrict__ y) {
  __shared__ __align__(16) unsigned short Ks[2][128 * 64];
  __shared__ __align__(16) unsigned short Vs[2][64 * 128];
  __shared__ __align__(16) unsigned short Ps[4][32 * 64];
  const int t = threadIdx.x;
  const int w = t >> 6, l = t & 63, lq = l & 31, hl = l >> 5;
  const int qsub = w & 1, par = w >> 1;
  const int id = blockIdx.x;
  const int bh = (id & 7) + 8 * ((id >> 3) & 3);
  const int uu = id >> 5;            // 0..15
  const int pp = uu & 7, qh = uu >> 3;
  const int b = bh >> 4, head = bh & 15;
  const int jA = 15 - pp, jB = pp;
  const int mA = jA + 1;             // + (jB+1) = 17
  const int NT = 17;
  const int fsA = 1 - (pp & 1);      // free ring slot during segment-A merge
  const float cexp = 0.18033688011112042f;  // (1/8)*log2(e)
  const float THR = 40.0f;

#define SWZ(r_) ((((r_) & 7) ^ (((r_) >> 3) & 3)) << 4)

  const int myswz = SWZ(lq);
  int offs[4];
#pragma unroll
  for (int s = 0; s < 4; s++) offs[s] = (32 * s + 16 * hl) ^ myswz;

  // --- staging addresses (pre-swizzled global, linear LDS dest = i*4096 + t*16)
  // K tile [128 kv][64 d] (128B rows): issue i covers rows 32i..32i+31
  const int u8 = t >> 3;  // 0..31
  const int ck = ((t & 7) * 16) ^ SWZ(u8);
  const char* gK = (const char*)(qkv + (size_t)(b * TT + u8) * N3 + CC + head * HSS) + ck;
  // V tile [64 d][128 kv] (256B rows): issue i covers rows 16i..16i+15
  const int v16 = t >> 4;         // 0..15
  const int ph = (t >> 3) & 1;    // kv parity half within row
  const int sbyte = (t & 7) * 16;
  const char* gV[4];
#pragma unroll
  for (int i = 0; i < 4; i++) {
    int row = i * 16 + v16;
    gV[i] = (const char*)vt + ((size_t)bh * HSS + row) * TT * 2 + ph * 128 +
            (sbyte ^ SWZ(row));
  }

#define STAGE(slot_, kvt_)                                                \
  do {                                                                    \
    size_t kb = (size_t)(kvt_) * (128 * N3 * 2);                          \
    size_t vb = (size_t)(kvt_) * 256;                                     \
    char* kd = (char*)Ks[slot_] + t * 16;                                 \
    char* vd = (char*)Vs[slot_] + t * 16;                                 \
    glds16(gK + kb, kd);                                                  \
    glds16(gK + kb + (size_t)32 * N3 * 2, kd + 4096);                     \
    glds16(gK + kb + (size_t)64 * N3 * 2, kd + 8192);                     \
    glds16(gK + kb + (size_t)96 * N3 * 2, kd + 12288);                    \
    glds16(gV[0] + vb, vd);                                               \
    glds16(gV[1] + vb, vd + 4096);                                        \
    glds16(gV[2] + vb, vd + 8192);                                        \
    glds16(gV[3] + vb, vd + 12288);                                       \
  } while (0)

#define WRITE_OUT()                                                       \
  do {                                                                    \
    float l_q = l_ln + __shfl_xor(l_ln, 32);                              \
    float inv = 1.0f / l_q;                                               \
    unsigned short* ybase = y + (size_t)(b * TT + q0w + lq) * CC + head * HSS; \
    _Pragma("unroll")                                                     \
    for (int g = 0; g < 4; g++) {                                         \
      ushort4 wv;                                                         \
      wv.x = f2bf(oa[4 * g + 0] * inv); wv.y = f2bf(oa[4 * g + 1] * inv); \
      wv.z = f2bf(oa[4 * g + 2] * inv); wv.w = f2bf(oa[4 * g + 3] * inv); \
      *(ushort4*)(ybase + 8 * g + 4 * hl) = wv;                           \
      ushort4 wv2;                                                        \
      wv2.x = f2bf(ob[4 * g + 0] * inv); wv2.y = f2bf(ob[4 * g + 1] * inv); \
      wv2.z = f2bf(ob[4 * g + 2] * inv); wv2.w = f2bf(ob[4 * g + 3] * inv); \
      *(ushort4*)(ybase + 32 + 8 * g + 4 * hl) = wv2;                     \
    }                                                                     \
  } while (0)

// parity merge staged through FREE ring slot fs_ (K slot: oa|ob, V slot: m|l)
#define MERGE(fs_)                                                        \
  do {                                                                    \
    __builtin_amdgcn_s_barrier();                                         \
    float* poolK = (float*)(Ks[fs_]);                                     \
    float* poolV = (float*)(Vs[fs_]);                                     \
    if (par) {                                                            \
      float* poa = poolK + qsub * 1024;                                   \
      float* pob = poolK + 2048 + qsub * 1024;                            \
      _Pragma("unroll")                                                   \
      for (int g = 0; g < 16; g++) { poa[g * 64 + l] = oa[g]; pob[g * 64 + l] = ob[g]; } \
      poolV[qsub * 64 + l] = m_s;                                         \
      poolV[128 + qsub * 64 + l] = l_ln;                                  \
    }                                                                     \
    asm volatile("s_waitcnt lgkmcnt(0)" ::: "memory");                    \
    __builtin_amdgcn_s_barrier();                                         \
    __builtin_amdgcn_sched_barrier(0);                                    \
    if (!par) {                                                           \
      float m1 = poolV[qsub * 64 + l], l1 = poolV[128 + qsub * 64 + l];   \
      float mstar = fmaxf(m_s, m1);                                       \
      float a0 = __builtin_amdgcn_exp2f((m_s - mstar) * cexp);            \
      float a1 = __builtin_amdgcn_exp2f((m1 - mstar) * cexp);             \
      const float* poa = poolK + qsub * 1024;                             \
      const float* pob = poolK + 2048 + qsub * 1024;                      \
      _Pragma("unroll")                                                   \
      for (int g = 0; g < 16; g++) {                                      \
        oa[g] = oa[g] * a0 + poa[g * 64 + l] * a1;                        \
        ob[g] = ob[g] * a0 + pob[g * 64 + l] * a1;                        \
      }                                                                   \
      l_ln = l_ln * a0 + l1 * a1;                                         \
      WRITE_OUT();                                                        \
    }                                                                     \
    __builtin_amdgcn_s_barrier();                                         \
  } while (0)

  // segment A state
  int q0w = jA * 128 + qh * 64 + qsub * 32;
  const unsigned short* qp = qkv + (size_t)(b * TT + q0w + lq) * N3 + head * HSS + hl * 8;
  bf16x8 qf0 = ld8(qp), qf1 = ld8(qp + 16), qf2 = ld8(qp + 32), qf3 = ld8(qp + 48);
  float m_s = -INFINITY, l_ln = 0.f;
  f32x16 oa = z16(), ob = z16();
  char* prow = (char*)Ps[w] + lq * 128;

  STAGE(0, 0);

  for (int seq = 0; seq < NT; ++seq) {
    if (seq == mA) {
      MERGE(fsA);  // finalize segment A (stage(mA) in flight in slot mA&1)
      q0w = jB * 128 + qh * 64 + qsub * 32;
      const unsigned short* qp2 = qkv + (size_t)(b * TT + q0w + lq) * N3 + head * HSS + hl * 8;
      qf0 = ld8(qp2); qf1 = ld8(qp2 + 16); qf2 = ld8(qp2 + 32); qf3 = ld8(qp2 + 48);
      m_s = -INFINITY; l_ln = 0.f;
      oa = z16(); ob = z16();
    }

    asm volatile("s_waitcnt vmcnt(0)" ::: "memory");
    __builtin_amdgcn_s_barrier();
    __builtin_amdgcn_sched_barrier(0);

    if (seq + 1 < NT) {
      int s2 = seq + 1;
      int kvt2 = (s2 < mA) ? s2 : (s2 - mA);
      STAGE((s2) & 1, kvt2);
    }
    __builtin_amdgcn_sched_barrier(0);

    const int kvt = (seq < mA) ? seq : (seq - mA);
    const int kv0w = kvt * 128 + 64 * par;
    if (kv0w > q0w + 31) continue;  // fully-masked for this wave (stage issued)

    const unsigned short* Kb = Ks[seq & 1];
    const unsigned short* Vb = Vs[seq & 1];

    // QK^T swapped: sa/sb hold S^T[kv][q=lq], kv=kv0w+(g&3)+8*(g>>2)+4*hl (+32 sb)
    const char* krA = (const char*)Kb + (64 * par + lq) * 128;
    const char* krB = krA + 32 * 128;
    f32x16 sa = z16(), sb = z16();
    __builtin_amdgcn_s_setprio(1);
    {
      bf16x8 ka, kb8;
      ka = ld8((const unsigned short*)(krA + offs[0]));
      kb8 = ld8((const unsigned short*)(krB + offs[0]));
      sa = mfma32(ka, qf0, sa); sb = mfma32(kb8, qf0, sb);
      ka = ld8((const unsigned short*)(krA + offs[1]));
      kb8 = ld8((const unsigned short*)(krB + offs[1]));
      sa = mfma32(ka, qf1, sa); sb = mfma32(kb8, qf1, sb);
      ka = ld8((const unsigned short*)(krA + offs[2]));
      kb8 = ld8((const unsigned short*)(krB + offs[2]));
      sa = mfma32(ka, qf2, sa); sb = mfma32(kb8, qf2, sb);
      ka = ld8((const unsigned short*)(krA + offs[3]));
      kb8 = ld8((const unsigned short*)(krB + offs[3]));
      sa = mfma32(ka, qf3, sa); sb = mfma32(kb8, qf3, sb);
    }
    __builtin_amdgcn_s_setprio(0);

    // causal mask near the diagonal
    if (kv0w + 63 > q0w) {
      const int q = q0w + lq;
#pragma unroll
      for (int g = 0; g < 16; g++) {
        int kvl = kv0w + (g & 3) + 8 * (g >> 2) + 4 * hl;
        if (kvl > q) sa[g] = -INFINITY;
        if (kvl + 32 > q) sb[g] = -INFINITY;
      }
    }

    // per-lane max + cross-half combine
    float tmax = -INFINITY;
#pragma unroll
    for (int g = 0; g < 16; g++) tmax = fmaxf(tmax, fmaxf(sa[g], sb[g]));
    tmax = fmaxf(tmax, __shfl_xor(tmax, 32));

    if (!__all(tmax <= m_s + THR)) {
      float m_new = fmaxf(m_s, tmax);
      float alpha = __builtin_amdgcn_exp2f((m_s - m_new) * cexp);
      l_ln *= alpha;
#pragma unroll
      for (int g = 0; g < 16; g++) { oa[g] *= alpha; ob[g] *= alpha; }
      m_s = m_new;
    }

    // exp in place; accumulate per-lane l
    const float mc = m_s * cexp;
    float tsum = 0.f;
#pragma unroll
    for (int g = 0; g < 16; g++) {
      sa[g] = __builtin_amdgcn_exp2f(__builtin_fmaf(sa[g], cexp, -mc));
      sb[g] = __builtin_amdgcn_exp2f(__builtin_fmaf(sb[g], cexp, -mc));
      tsum += sa[g] + sb[g];
    }
    l_ln += tsum;

    // P -> LDS bounce (wave-private)
#pragma unroll
    for (int u2 = 0; u2 < 4; u2++) {
      bf16x4 w0, w1;
#pragma unroll
      for (int r = 0; r < 4; r++) { w0[r] = (__bf16)sa[4 * u2 + r]; w1[r] = (__bf16)sb[4 * u2 + r]; }
      *(bf16x4*)(prow + ((16 * u2 + 8 * hl) ^ myswz)) = w0;
      *(bf16x4*)(prow + ((64 + 16 * u2 + 8 * hl) ^ myswz)) = w1;
    }
    asm volatile("s_waitcnt lgkmcnt(0)" ::: "memory");
    __builtin_amdgcn_sched_barrier(0);
    bf16x8 pf0 = ld8((const unsigned short*)(prow + offs[0]));
    bf16x8 pf1 = ld8((const unsigned short*)(prow + offs[1]));
    bf16x8 pf2 = ld8((const unsigned short*)(prow + offs[2]));
    bf16x8 pf3 = ld8((const unsigned short*)(prow + offs[3]));

    // PV on this wave's 64-kv parity half; V rows lq / lq+32 (256B rows)
    const char* vrA = (const char*)Vb + lq * 256 + par * 128;
    const char* vrB = vrA + 32 * 256;
    __builtin_amdgcn_s_setprio(1);
    {
      bf16x8 va, vb8;
      va = ld8((const unsigned short*)(vrA + offs[0]));
      vb8 = ld8((const unsigned short*)(vrB + offs[0]));
      oa = mfma32(va, pf0, oa); ob = mfma32(vb8, pf0, ob);
      va = ld8((const unsigned short*)(vrA + offs[1]));
      vb8 = ld8((const unsigned short*)(vrB + offs[1]));
      oa = mfma32(va, pf1, oa); ob = mfma32(vb8, pf1, ob);
      va = ld8((const unsigned short*)(vrA + offs[2]));
      vb8 = ld8((const unsigned short*)(vrB + offs[2]));
      oa = mfma32(va, pf2, oa); ob = mfma32(vb8, pf2, ob);
      va = ld8((const unsigned short*)(vrA + offs[3]));
      vb8 = ld8((const unsigned short*)(vrB + offs[3]));
      oa = mfma32(va, pf3, oa); ob = mfma32(vb8, pf3, ob);
    }
    __builtin_amdgcn_s_setprio(0);
  }

  MERGE(1);  // finalize segment B (no staging in flight; slot 1 free)
#undef STAGE
#undef WRITE_OUT
#undef MERGE
#undef SWZ
}

extern "C" void kernel_launch(void* const* d_in, const int* in_sizes, int n_in,
                              void* d_out, int out_size, void* d_ws, size_t ws_size,
                              hipStream_t stream) {
  const float* x = (const float*)d_in[0];
  const float* W_attn = (const float*)d_in[1];
  const float* b_attn = (const float*)d_in[2];
  const float* W_proj = (const float*)d_in[3];
  const float* b_proj = (const float*)d_in[4];

  char* ws = (char*)d_ws;
  unsigned short* xb   = (unsigned short*)(ws);                       // 8 MB
  unsigned short* wabt = (unsigned short*)(ws + 8388608);             // 6 MB  [3072][1024]
  unsigned short* wpbt = (unsigned short*)(ws + 14680064);            // 2 MB  [1024][1024]
  unsigned short* qkvb = (unsigned short*)(ws + 16777216);            // 24 MB [4096][3072]
  unsigned short* vt   = (unsigned short*)(ws + 41943040);            // 8 MB  [32][64][2048]
  unsigned short* yb   = (unsigned short*)(ws + 50331648);            // 8 MB  [4096][1024]

  k_conv<<<2048, 256, 0, stream>>>(x, xb, BT * CC / 4);
  k_transp<<<dim3(N3 / 32, CC / 32), dim3(32, 8), 0, stream>>>(W_attn, wabt, CC, N3);
  k_transp<<<dim3(CC / 32, CC / 32), dim3(32, 8), 0, stream>>>(W_proj, wpbt, CC, CC);
  // QKV: M=4096, N=3072 -> 32x24 = 768 blocks (768 % 8 == 0)
  k_gemm<1><<<dim3(768), 256, 0, stream>>>(xb, wabt, b_attn, qkvb, N3, CC, 24);
  k_vt<<<dim3(TT / 64, BB * NHH), dim3(64, 4), 0, stream>>>(qkvb, vt);
  k_attn<<<dim3(512), 256, 0, stream>>>(qkvb, vt, yb);
  // proj: M=4096, N=1024 -> 32x8 = 256 blocks (256 % 8 == 0)
  k_gemm<0><<<dim3(256), 256, 0, stream>>>(yb, wpbt, b_proj, d_out, CC, CC, 8);
}

// Round 11
// 119.292 us; speedup vs baseline: 1.0334x; 1.0334x over previous
//
#include <hip/hip_runtime.h>
#include <hip/hip_bf16.h>
#include <stdint.h>

#define DEV static __device__ __forceinline__

typedef __attribute__((ext_vector_type(8))) __bf16 bf16x8;
typedef __attribute__((ext_vector_type(4))) __bf16 bf16x4;
typedef __attribute__((ext_vector_type(4))) float f32x4;
typedef __attribute__((ext_vector_type(16))) float f32x16;

// B=2, T=2048, C=1024, NH=16, HS=64
#define BB 2
#define TT 2048
#define CC 1024
#define NHH 16
#define HSS 64
#define BT 4096
#define N3 3072

DEV unsigned short f2bf(float f) {
  union { float f; uint32_t u; } v; v.f = f;
  uint32_t r = v.u + 0x7FFFu + ((v.u >> 16) & 1u);
  return (unsigned short)(r >> 16);
}

typedef const __attribute__((address_space(1))) unsigned int* gas_t;
typedef __attribute__((address_space(3))) unsigned int* las_t;

DEV void glds16(const void* g, void* l) {
  __builtin_amdgcn_global_load_lds((gas_t)g, (las_t)l, 16, 0, 0);
}

DEV f32x4 mfma16(bf16x8 a, bf16x8 b, f32x4 c) {
  return __builtin_amdgcn_mfma_f32_16x16x32_bf16(a, b, c, 0, 0, 0);
}
DEV f32x16 mfma32(bf16x8 a, bf16x8 b, f32x16 c) {
  return __builtin_amdgcn_mfma_f32_32x32x16_bf16(a, b, c, 0, 0, 0);
}

DEV bf16x8 ld8(const unsigned short* p) { return *(const bf16x8*)p; }

DEV f32x16 z16() {
  f32x16 v;
#pragma unroll
  for (int i = 0; i < 16; i++) v[i] = 0.f;
  return v;
}

// ---------- fp32 -> bf16 convert (vectorized) ----------
__global__ void k_conv(const float* __restrict__ in, unsigned short* __restrict__ out, int n4) {
  int i = blockIdx.x * blockDim.x + threadIdx.x;
  int stride = gridDim.x * blockDim.x;
  for (; i < n4; i += stride) {
    float4 v = ((const float4*)in)[i];
    ushort4 o;
    o.x = f2bf(v.x); o.y = f2bf(v.y); o.z = f2bf(v.z); o.w = f2bf(v.w);
    ((ushort4*)out)[i] = o;
  }
}

// ---------- transpose+convert: in [K][N] f32 -> out [N][K] bf16 ----------
__global__ void k_transp(const float* __restrict__ in, unsigned short* __restrict__ out,
                         int K, int N) {
  __shared__ float tile[32][33];
  int n0 = blockIdx.x * 32, k0 = blockIdx.y * 32;
  int tx = threadIdx.x, ty = threadIdx.y;  // (32,8)
  for (int r = ty; r < 32; r += 8)
    tile[r][tx] = in[(size_t)(k0 + r) * N + n0 + tx];
  __syncthreads();
  for (int r = ty; r < 32; r += 8)
    out[(size_t)(n0 + r) * K + k0 + tx] = f2bf(tile[tx][r]);
}

// ---------- GEMM: A[M][K] bf16, Bt[N][K] bf16, bias f32[N] ----------
// 128x128 tile, BK=64 (128B LDS rows, XOR-swizzled), ring-2 LDS (64KB),
// one barrier per K-step, stage issued right after barrier (latency covered by
// previous step's compute + 2 blocks/CU). XCD-chunked bijective block swizzle.
template <int OUT_BF16>
__global__ __launch_bounds__(256) void k_gemm(const unsigned short* __restrict__ A,
                                              const unsigned short* __restrict__ Bt,
                                              const float* __restrict__ bias,
                                              void* __restrict__ Cout,
                                              int N, int K, int gx) {
  __shared__ __align__(16) unsigned short As[2][128 * 64];
  __shared__ __align__(16) unsigned short Bs[2][128 * 64];
  const int t = threadIdx.x;
  const int wave = t >> 6, l = t & 63, lr = l & 15, lg = l >> 4;
  const int cpx = gridDim.x >> 3;
  const int sw = ((int)blockIdx.x & 7) * cpx + ((int)blockIdx.x >> 3);
  const int m0 = (sw / gx) * 128, n0 = (sw % gx) * 128;
  const int wm = wave >> 1, wn = wave & 1;

  f32x4 acc[4][4] = {};

  // read-side swizzle per fragment i: row = {wm|wn}*64 + i*16 + lr
  // row&7 = lr&7 ; (row>>3)&3 = (2i + (lr>>3)) & 3   (64 ≡ 0 mod 32 rows)
  int swz[4];
#pragma unroll
  for (int i = 0; i < 4; i++)
    swz[i] = ((lr & 7) ^ ((2 * i + (lr >> 3)) & 3)) << 4;

  // staging: issue i covers LDS bytes i*4096 + t*16 -> row = i*32 + (t>>3),
  // col = ((t&7)*16) ^ SWZ(row); SWZ(row) is i-independent (32 | i*32).
  const int strow = t >> 3;
  const int stcol = ((t & 7) * 16) ^ ((((t >> 3) & 7) ^ ((t >> 6) & 3)) << 4);
  const char* gAc = (const char*)(A + (size_t)(m0 + strow) * K) + stcol;
  const char* gBc = (const char*)(Bt + (size_t)(n0 + strow) * K) + stcol;
  const size_t rstep = (size_t)32 * K * 2;  // 32 rows in bytes

#define GSTAGE(buf_, k0_)                                                 \
  do {                                                                    \
    const char* a0 = gAc + (size_t)(k0_) * 2;                             \
    const char* b0 = gBc + (size_t)(k0_) * 2;                             \
    char* ad = (char*)As[buf_] + t * 16;                                  \
    char* bd = (char*)Bs[buf_] + t * 16;                                  \
    glds16(a0, ad);                                                       \
    glds16(a0 + rstep, ad + 4096);                                        \
    glds16(a0 + 2 * rstep, ad + 8192);                                    \
    glds16(a0 + 3 * rstep, ad + 12288);                                   \
    glds16(b0, bd);                                                       \
    glds16(b0 + rstep, bd + 4096);                                        \
    glds16(b0 + 2 * rstep, bd + 8192);                                    \
    glds16(b0 + 3 * rstep, bd + 12288);                                   \
  } while (0)

  const int nst = K >> 6;
  GSTAGE(0, 0);

  for (int st = 0; st < nst; ++st) {
    asm volatile("s_waitcnt vmcnt(0)" ::: "memory");
    __builtin_amdgcn_s_barrier();
    __builtin_amdgcn_sched_barrier(0);
    if (st + 1 < nst) GSTAGE((st + 1) & 1, (st + 1) * 64);
    __builtin_amdgcn_sched_barrier(0);

    const char* Ab = (const char*)As[st & 1];
    const char* Bb = (const char*)Bs[st & 1];
#pragma unroll
    for (int s = 0; s < 2; s++) {
      bf16x8 av[4], bv[4];
#pragma unroll
      for (int i = 0; i < 4; i++) {
        int ko = (s * 64 + lg * 16) ^ swz[i];
        av[i] = ld8((const unsigned short*)(Ab + (wm * 64 + i * 16 + lr) * 128 + ko));
        bv[i] = ld8((const unsigned short*)(Bb + (wn * 64 + i * 16 + lr) * 128 + ko));
      }
#pragma unroll
      for (int i = 0; i < 4; i++)
#pragma unroll
        for (int j = 0; j < 4; j++)
          acc[i][j] = mfma16(av[i], bv[j], acc[i][j]);
    }
  }
#undef GSTAGE

#pragma unroll
  for (int j2 = 0; j2 < 4; j2++) {
    int col = n0 + wn * 64 + j2 * 16 + lr;
    float bv_ = bias[col];
#pragma unroll
    for (int i = 0; i < 4; i++) {
      int row = m0 + wm * 64 + i * 16 + lg * 4;
#pragma unroll
      for (int r = 0; r < 4; r++) {
        float v = acc[i][j2][r] + bv_;
        if (OUT_BF16)
          ((unsigned short*)Cout)[(size_t)(row + r) * N + col] = f2bf(v);
        else
          ((float*)Cout)[(size_t)(row + r) * N + col] = v;
      }
    }
  }
}

// ---------- per-head V transpose: qkv[b][t][2048+h*64+d] -> vt[bh][d][t] ----------
__global__ void k_vt(const unsigned short* __restrict__ qkv, unsigned short* __restrict__ vt) {
  __shared__ unsigned short tile[64][65];
  int bh = blockIdx.y, t0 = blockIdx.x * 64;
  int b = bh >> 4, h = bh & 15;
  int tx = threadIdx.x, ty = threadIdx.y;  // (64,4)
  const unsigned short* src = qkv + (size_t)(b * TT + t0) * N3 + 2 * CC + h * HSS;
  for (int r = ty; r < 64; r += 4)
    tile[r][tx] = src[(size_t)r * N3 + tx];
  __syncthreads();
  unsigned short* dst = vt + (size_t)bh * HSS * TT + t0;
  for (int r = ty; r < 64; r += 4)
    dst[(size_t)r * TT + tx] = tile[tx][r];
}

// ---------- flash attention: 8 waves, kv-parity split, paired q-tiles ----------
// (round-9 version, proven 42us) 256 blocks x 8 waves. Block = (bh, p):
// segment A = q-tile 15-p, then B = p. Wave = (qsub 0..3, par 0..1). Ring-3
// K/V LDS, depth-1 prefetch + counted vmcnt(4). Parity merge through Ps.
__global__ __launch_bounds__(512) void k_attn(const unsigned short* __restrict__ qkv,
                                              const unsigned short* __restrict__ vt,
                                              unsigned short* __restrict__ y) {
  __shared__ __align__(16) unsigned short Ks[3][128 * 64];
  __shared__ __align__(16) unsigned short Vs[3][128 * 64];
  __shared__ __align__(16) unsigned short Ps[8][32 * 64];
  __shared__ float Msh[4][64];
  __shared__ float Lsh[4][64];
  const int t = threadIdx.x;
  const int w = t >> 6, l = t & 63, lq = l & 31, hl = l >> 5;
  const int qsub = w & 3, par = w >> 2;
  const int id = blockIdx.x;
  const int bh = (id & 7) + 8 * ((id >> 3) & 3);
  const int p = id >> 5;  // 0..7
  const int b = bh >> 4, head = bh & 15;
  const int jA = 15 - p, jB = p;
  const int mA = jA + 1;        // + (jB+1) = 17 macro-steps
  const int NT = 17;
  const float cexp = 0.18033688011112042f;  // (1/8)*log2(e)
  const float THR = 40.0f;

#define SWZ(r_) ((((r_) & 7) ^ (((r_) >> 3) & 3)) << 4)

  const int myswz = SWZ(lq);
  int offs[4];
#pragma unroll
  for (int s = 0; s < 4; s++) offs[s] = (32 * s + 16 * hl) ^ myswz;

  // staging: two glds16 issues per array; linear LDS off = i*8192 + w*1024 + l*16
  const int off0 = w * 1024 + l * 16;
  const int off1 = 8192 + w * 1024 + l * 16;
  const int rk0 = off0 >> 7, rk1 = off1 >> 7;          // K rows 0..127
  const int ck0 = (off0 & 127) ^ SWZ(rk0), ck1 = (off1 & 127) ^ SWZ(rk1);
  const int rv0 = rk0 & 63, rv1 = rk1 & 63;            // V rows 0..63, subtile = i
  const int cv0 = (off0 & 127) ^ SWZ(rv0), cv1 = (off1 & 127) ^ SWZ(rv1);
  const char* gK0 = (const char*)(qkv + (size_t)(b * TT + rk0) * N3 + CC + head * HSS) + ck0;
  const char* gK1 = (const char*)(qkv + (size_t)(b * TT + rk1) * N3 + CC + head * HSS) + ck1;
  const char* gV0 = (const char*)(vt + ((size_t)bh * HSS + rv0) * TT) + cv0;        // kv 0..63
  const char* gV1 = (const char*)(vt + ((size_t)bh * HSS + rv1) * TT + 64) + cv1;   // kv 64..127
  const int dK0 = w * 1024, dK1 = 8192 + w * 1024;

#define STAGE(slot_, kvt_)                                                \
  do {                                                                    \
    size_t kb = (size_t)(kvt_) * (128 * N3 * 2);                          \
    size_t vb = (size_t)(kvt_) * 256;                                     \
    glds16(gK0 + kb, (char*)Ks[slot_] + dK0);                             \
    glds16(gK1 + kb, (char*)Ks[slot_] + dK1);                             \
    glds16(gV0 + vb, (char*)Vs[slot_] + dK0);                             \
    glds16(gV1 + vb, (char*)Vs[slot_] + dK1);                             \
  } while (0)

#define WRITE_OUT()                                                       \
  do {                                                                    \
    float l_q = l_ln + __shfl_xor(l_ln, 32);                              \
    float inv = 1.0f / l_q;                                               \
    unsigned short* ybase = y + (size_t)(b * TT + q0w + lq) * CC + head * HSS; \
    _Pragma("unroll")                                                     \
    for (int g = 0; g < 4; g++) {                                         \
      ushort4 wv;                                                         \
      wv.x = f2bf(oa[4 * g + 0] * inv); wv.y = f2bf(oa[4 * g + 1] * inv); \
      wv.z = f2bf(oa[4 * g + 2] * inv); wv.w = f2bf(oa[4 * g + 3] * inv); \
      *(ushort4*)(ybase + 8 * g + 4 * hl) = wv;                           \
      ushort4 wv2;                                                        \
      wv2.x = f2bf(ob[4 * g + 0] * inv); wv2.y = f2bf(ob[4 * g + 1] * inv); \
      wv2.z = f2bf(ob[4 * g + 2] * inv); wv2.w = f2bf(ob[4 * g + 3] * inv); \
      *(ushort4*)(ybase + 32 + 8 * g + 4 * hl) = wv2;                     \
    }                                                                     \
  } while (0)

// cross-parity merge: par1 writes (oa,ob,m,l) through Ps; par0 combines + stores y
#define MERGE()                                                           \
  do {                                                                    \
    __builtin_amdgcn_s_barrier();                                         \
    if (par) {                                                            \
      float* poa = (float*)Ps[w];                                         \
      float* pob = (float*)Ps[w - 4];                                     \
      _Pragma("unroll")                                                   \
      for (int g = 0; g < 16; g++) { poa[g * 64 + l] = oa[g]; pob[g * 64 + l] = ob[g]; } \
      Msh[qsub][l] = m_s; Lsh[qsub][l] = l_ln;                            \
    }                                                                     \
    asm volatile("s_waitcnt lgkmcnt(0)" ::: "memory");                    \
    __builtin_amdgcn_s_barrier();                                         \
    __builtin_amdgcn_sched_barrier(0);                                    \
    if (!par) {                                                           \
      float m1 = Msh[qsub][l], l1 = Lsh[qsub][l];                         \
      float mstar = fmaxf(m_s, m1);                                       \
      float a0 = __builtin_amdgcn_exp2f((m_s - mstar) * cexp);            \
      float a1 = __builtin_amdgcn_exp2f((m1 - mstar) * cexp);             \
      const float* poa = (const float*)Ps[w + 4];                         \
      const float* pob = (const float*)Ps[w];                             \
      _Pragma("unroll")                                                   \
      for (int g = 0; g < 16; g++) {                                      \
        oa[g] = oa[g] * a0 + poa[g * 64 + l] * a1;                        \
        ob[g] = ob[g] * a0 + pob[g * 64 + l] * a1;                        \
      }                                                                   \
      l_ln = l_ln * a0 + l1 * a1;                                         \
      WRITE_OUT();                                                        \
    }                                                                     \
    __builtin_amdgcn_s_barrier();                                         \
  } while (0)

  // segment A state
  int q0w = jA * 128 + qsub * 32;
  const unsigned short* qp = qkv + (size_t)(b * TT + q0w + lq) * N3 + head * HSS + hl * 8;
  bf16x8 qf0 = ld8(qp), qf1 = ld8(qp + 16), qf2 = ld8(qp + 32), qf3 = ld8(qp + 48);
  float m_s = -INFINITY, l_ln = 0.f;
  f32x16 oa = z16(), ob = z16();
  char* prow = (char*)Ps[w] + lq * 128;

  STAGE(0, 0);
  int cur = 0;

  for (int seq = 0; seq < NT; ++seq) {
    if (seq == mA) {
      MERGE();  // finalize segment A; y written by par0
      q0w = jB * 128 + qsub * 32;
      const unsigned short* qp2 = qkv + (size_t)(b * TT + q0w + lq) * N3 + head * HSS + hl * 8;
      qf0 = ld8(qp2); qf1 = ld8(qp2 + 16); qf2 = ld8(qp2 + 32); qf3 = ld8(qp2 + 48);
      m_s = -INFINITY; l_ln = 0.f;
      oa = z16(); ob = z16();
    }

    const int kvt = (seq < mA) ? seq : (seq - mA);
    if (seq + 1 < NT) {
      int s2 = seq + 1;
      int kvt2 = (s2 < mA) ? s2 : (s2 - mA);
      int nxt = (cur == 2) ? 0 : cur + 1;
      STAGE(nxt, kvt2);
      __builtin_amdgcn_sched_barrier(0);
      asm volatile("s_waitcnt vmcnt(4)" ::: "memory");
    } else {
      asm volatile("s_waitcnt vmcnt(0)" ::: "memory");
    }
    __builtin_amdgcn_s_barrier();
    __builtin_amdgcn_sched_barrier(0);

    const int mybuf = cur;
    cur = (cur == 2) ? 0 : cur + 1;

    const int kv0w = kvt * 128 + 64 * par;
    if (kv0w > q0w + 31) continue;  // fully-masked for this wave (barriers done)

    const unsigned short* Kb = Ks[mybuf];
    const unsigned short* Vb = Vs[mybuf];

    // QK^T swapped: sa/sb hold S^T[kv][q=lq], kv=kv0w+(g&3)+8*(g>>2)+4*hl (+32 sb)
    const char* krA = (const char*)Kb + (64 * par + lq) * 128;
    const char* krB = krA + 32 * 128;
    f32x16 sa = z16(), sb = z16();
    __builtin_amdgcn_s_setprio(1);
    {
      bf16x8 ka, kb8;
      ka = ld8((const unsigned short*)(krA + offs[0]));
      kb8 = ld8((const unsigned short*)(krB + offs[0]));
      sa = mfma32(ka, qf0, sa); sb = mfma32(kb8, qf0, sb);
      ka = ld8((const unsigned short*)(krA + offs[1]));
      kb8 = ld8((const unsigned short*)(krB + offs[1]));
      sa = mfma32(ka, qf1, sa); sb = mfma32(kb8, qf1, sb);
      ka = ld8((const unsigned short*)(krA + offs[2]));
      kb8 = ld8((const unsigned short*)(krB + offs[2]));
      sa = mfma32(ka, qf2, sa); sb = mfma32(kb8, qf2, sb);
      ka = ld8((const unsigned short*)(krA + offs[3]));
      kb8 = ld8((const unsigned short*)(krB + offs[3]));
      sa = mfma32(ka, qf3, sa); sb = mfma32(kb8, qf3, sb);
    }
    __builtin_amdgcn_s_setprio(0);

    // causal mask near the diagonal
    if (kv0w + 63 > q0w) {
      const int q = q0w + lq;
#pragma unroll
      for (int g = 0; g < 16; g++) {
        int kvl = kv0w + (g & 3) + 8 * (g >> 2) + 4 * hl;
        if (kvl > q) sa[g] = -INFINITY;
        if (kvl + 32 > q) sb[g] = -INFINITY;
      }
    }

    // per-lane max + cross-half combine
    float tmax = -INFINITY;
#pragma unroll
    for (int g = 0; g < 16; g++) tmax = fmaxf(tmax, fmaxf(sa[g], sb[g]));
    tmax = fmaxf(tmax, __shfl_xor(tmax, 32));

    if (!__all(tmax <= m_s + THR)) {
      float m_new = fmaxf(m_s, tmax);
      float alpha = __builtin_amdgcn_exp2f((m_s - m_new) * cexp);
      l_ln *= alpha;
#pragma unroll
      for (int g = 0; g < 16; g++) { oa[g] *= alpha; ob[g] *= alpha; }
      m_s = m_new;
    }

    // exp in place; accumulate per-lane l
    const float mc = m_s * cexp;
    float tsum = 0.f;
#pragma unroll
    for (int g = 0; g < 16; g++) {
      sa[g] = __builtin_amdgcn_exp2f(__builtin_fmaf(sa[g], cexp, -mc));
      sb[g] = __builtin_amdgcn_exp2f(__builtin_fmaf(sb[g], cexp, -mc));
      tsum += sa[g] + sb[g];
    }
    l_ln += tsum;

    // P -> LDS bounce (wave-private)
#pragma unroll
    for (int u2 = 0; u2 < 4; u2++) {
      bf16x4 w0, w1;
#pragma unroll
      for (int r = 0; r < 4; r++) { w0[r] = (__bf16)sa[4 * u2 + r]; w1[r] = (__bf16)sb[4 * u2 + r]; }
      *(bf16x4*)(prow + ((16 * u2 + 8 * hl) ^ myswz)) = w0;
      *(bf16x4*)(prow + ((64 + 16 * u2 + 8 * hl) ^ myswz)) = w1;
    }
    asm volatile("s_waitcnt lgkmcnt(0)" ::: "memory");
    __builtin_amdgcn_sched_barrier(0);
    bf16x8 pf0 = ld8((const unsigned short*)(prow + offs[0]));
    bf16x8 pf1 = ld8((const unsigned short*)(prow + offs[1]));
    bf16x8 pf2 = ld8((const unsigned short*)(prow + offs[2]));
    bf16x8 pf3 = ld8((const unsigned short*)(prow + offs[3]));

    // PV on this wave's V subtile (kv parity half)
    const char* vrA = (const char*)Vb + par * 8192 + lq * 128;
    const char* vrB = vrA + 32 * 128;
    __builtin_amdgcn_s_setprio(1);
    {
      bf16x8 va, vb8;
      va = ld8((const unsigned short*)(vrA + offs[0]));
      vb8 = ld8((const unsigned short*)(vrB + offs[0]));
      oa = mfma32(va, pf0, oa); ob = mfma32(vb8, pf0, ob);
      va = ld8((const unsigned short*)(vrA + offs[1]));
      vb8 = ld8((const unsigned short*)(vrB + offs[1]));
      oa = mfma32(va, pf1, oa); ob = mfma32(vb8, pf1, ob);
      va = ld8((const unsigned short*)(vrA + offs[2]));
      vb8 = ld8((const unsigned short*)(vrB + offs[2]));
      oa = mfma32(va, pf2, oa); ob = mfma32(vb8, pf2, ob);
      va = ld8((const unsigned short*)(vrA + offs[3]));
      vb8 = ld8((const unsigned short*)(vrB + offs[3]));
      oa = mfma32(va, pf3, oa); ob = mfma32(vb8, pf3, ob);
    }
    __builtin_amdgcn_s_setprio(0);
  }

  MERGE();  // finalize segment B
#undef STAGE
#undef WRITE_OUT
#undef MERGE
#undef SWZ
}

extern "C" void kernel_launch(void* const* d_in, const int* in_sizes, int n_in,
                              void* d_out, int out_size, void* d_ws, size_t ws_size,
                              hipStream_t stream) {
  const float* x = (const float*)d_in[0];
  const float* W_attn = (const float*)d_in[1];
  const float* b_attn = (const float*)d_in[2];
  const float* W_proj = (const float*)d_in[3];
  const float* b_proj = (const float*)d_in[4];

  char* ws = (char*)d_ws;
  unsigned short* xb   = (unsigned short*)(ws);                       // 8 MB
  unsigned short* wabt = (unsigned short*)(ws + 8388608);             // 6 MB  [3072][1024]
  unsigned short* wpbt = (unsigned short*)(ws + 14680064);            // 2 MB  [1024][1024]
  unsigned short* qkvb = (unsigned short*)(ws + 16777216);            // 24 MB [4096][3072]
  unsigned short* vt   = (unsigned short*)(ws + 41943040);            // 8 MB  [32][64][2048]
  unsigned short* yb   = (unsigned short*)(ws + 50331648);            // 8 MB  [4096][1024]

  k_conv<<<2048, 256, 0, stream>>>(x, xb, BT * CC / 4);
  k_transp<<<dim3(N3 / 32, CC / 32), dim3(32, 8), 0, stream>>>(W_attn, wabt, CC, N3);
  k_transp<<<dim3(CC / 32, CC / 32), dim3(32, 8), 0, stream>>>(W_proj, wpbt, CC, CC);
  // QKV: M=4096, N=3072 -> 32x24 = 768 blocks (768 % 8 == 0)
  k_gemm<1><<<dim3(768), 256, 0, stream>>>(xb, wabt, b_attn, qkvb, N3, CC, 24);
  k_vt<<<dim3(TT / 64, BB * NHH), dim3(64, 4), 0, stream>>>(qkvb, vt);
  k_attn<<<dim3(256), 512, 0, stream>>>(qkvb, vt, yb);
  // proj: M=4096, N=1024 -> 32x8 = 256 blocks (256 % 8 == 0)
  k_gemm<0><<<dim3(256), 256, 0, stream>>>(yb, wpbt, b_proj, d_out, CC, CC, 8);
}

// Round 12
// 116.196 us; speedup vs baseline: 1.0609x; 1.0266x over previous
//
#include <hip/hip_runtime.h>
#include <hip/hip_bf16.h>
#include <stdint.h>

#define DEV static __device__ __forceinline__

typedef __attribute__((ext_vector_type(8))) __bf16 bf16x8;
typedef __attribute__((ext_vector_type(4))) __bf16 bf16x4;
typedef __attribute__((ext_vector_type(4))) float f32x4;
typedef __attribute__((ext_vector_type(16))) float f32x16;

// B=2, T=2048, C=1024, NH=16, HS=64
#define BB 2
#define TT 2048
#define CC 1024
#define NHH 16
#define HSS 64
#define BT 4096
#define N3 3072

DEV unsigned short f2bf(float f) {
  union { float f; uint32_t u; } v; v.f = f;
  uint32_t r = v.u + 0x7FFFu + ((v.u >> 16) & 1u);
  return (unsigned short)(r >> 16);
}

typedef const __attribute__((address_space(1))) unsigned int* gas_t;
typedef __attribute__((address_space(3))) unsigned int* las_t;

DEV void glds16(const void* g, void* l) {
  __builtin_amdgcn_global_load_lds((gas_t)g, (las_t)l, 16, 0, 0);
}

DEV f32x4 mfma16(bf16x8 a, bf16x8 b, f32x4 c) {
  return __builtin_amdgcn_mfma_f32_16x16x32_bf16(a, b, c, 0, 0, 0);
}
DEV f32x16 mfma32(bf16x8 a, bf16x8 b, f32x16 c) {
  return __builtin_amdgcn_mfma_f32_32x32x16_bf16(a, b, c, 0, 0, 0);
}

DEV bf16x8 ld8(const unsigned short* p) { return *(const bf16x8*)p; }

DEV f32x16 z16() {
  f32x16 v;
#pragma unroll
  for (int i = 0; i < 16; i++) v[i] = 0.f;
  return v;
}

// ---------- fp32 -> bf16 convert (vectorized) ----------
__global__ void k_conv(const float* __restrict__ in, unsigned short* __restrict__ out, int n4) {
  int i = blockIdx.x * blockDim.x + threadIdx.x;
  int stride = gridDim.x * blockDim.x;
  for (; i < n4; i += stride) {
    float4 v = ((const float4*)in)[i];
    ushort4 o;
    o.x = f2bf(v.x); o.y = f2bf(v.y); o.z = f2bf(v.z); o.w = f2bf(v.w);
    ((ushort4*)out)[i] = o;
  }
}

// ---------- transpose+convert: in [K][N] f32 -> out [N][K] bf16 ----------
__global__ void k_transp(const float* __restrict__ in, unsigned short* __restrict__ out,
                         int K, int N) {
  __shared__ float tile[32][33];
  int n0 = blockIdx.x * 32, k0 = blockIdx.y * 32;
  int tx = threadIdx.x, ty = threadIdx.y;  // (32,8)
  for (int r = ty; r < 32; r += 8)
    tile[r][tx] = in[(size_t)(k0 + r) * N + n0 + tx];
  __syncthreads();
  for (int r = ty; r < 32; r += 8)
    out[(size_t)(n0 + r) * K + k0 + tx] = f2bf(tile[tx][r]);
}

// ---------- GEMM: A[M][K] bf16, Bt[N][K] bf16, bias f32[N] ----------
// 128x128 tile, BK=32, ring-3 LDS (48KB -> 3 blocks/CU), depth-2 prefetch,
// counted vmcnt(8): stage(t) gets ~2 full steps to land. Two non-draining
// barriers per step. XCD-chunked bijective block swizzle (gridDim.x % 8 == 0).
template <int OUT_BF16>
__global__ __launch_bounds__(256) void k_gemm(const unsigned short* __restrict__ A,
                                              const unsigned short* __restrict__ Bt,
                                              const float* __restrict__ bias,
                                              void* __restrict__ Cout,
                                              int N, int K, int gx) {
  __shared__ __align__(16) unsigned short As[3][128 * 32];
  __shared__ __align__(16) unsigned short Bs[3][128 * 32];
  const int t = threadIdx.x;
  const int wave = t >> 6, l = t & 63, lr = l & 15, lg = l >> 4;
  const int cpx = gridDim.x >> 3;
  const int sw = ((int)blockIdx.x & 7) * cpx + ((int)blockIdx.x >> 3);
  const int m0 = (sw / gx) * 128, n0 = (sw % gx) * 128;
  const int wm = wave >> 1, wn = wave & 1;

  f32x4 acc[4][4] = {};

  // staging map: thread t -> row t>>2 (issue0) / 64+(t>>2) (issue1), chunk (t&3)*16B
  const unsigned short* gA = A + (size_t)(m0 + (t >> 2)) * K + (t & 3) * 8;
  const unsigned short* gB = Bt + (size_t)(n0 + (t >> 2)) * K + (t & 3) * 8;
  const size_t rstep = (size_t)64 * K;

#define GSTAGE(buf_, k_)                                                  \
  do {                                                                    \
    char* ad = (char*)As[buf_] + t * 16;                                  \
    char* bd = (char*)Bs[buf_] + t * 16;                                  \
    glds16(gA + (k_), ad);                                                \
    glds16(gA + rstep + (k_), ad + 4096);                                 \
    glds16(gB + (k_), bd);                                                \
    glds16(gB + rstep + (k_), bd + 4096);                                 \
  } while (0)

  const int nst = K >> 5;
  GSTAGE(0, 0);
  GSTAGE(1, 32);

  for (int st = 0; st < nst; ++st) {
    __builtin_amdgcn_s_barrier();          // A: guards slot (st+2)%3 overwrite
    __builtin_amdgcn_sched_barrier(0);
    if (st + 2 < nst) GSTAGE((st + 2) % 3, (st + 2) * 32);
    __builtin_amdgcn_sched_barrier(0);
    if (st + 2 < nst)      asm volatile("s_waitcnt vmcnt(8)" ::: "memory");
    else if (st + 1 < nst) asm volatile("s_waitcnt vmcnt(4)" ::: "memory");
    else                   asm volatile("s_waitcnt vmcnt(0)" ::: "memory");
    __builtin_amdgcn_s_barrier();          // B: all waves' stage(st) visible
    __builtin_amdgcn_sched_barrier(0);

    const unsigned short* Ab = As[st % 3];
    const unsigned short* Bb = Bs[st % 3];
    bf16x8 av[4], bv[4];
#pragma unroll
    for (int i = 0; i < 4; i++) {
      av[i] = ld8(Ab + (wm * 64 + i * 16 + lr) * 32 + lg * 8);
      bv[i] = ld8(Bb + (wn * 64 + i * 16 + lr) * 32 + lg * 8);
    }
    __builtin_amdgcn_s_setprio(1);
#pragma unroll
    for (int i = 0; i < 4; i++)
#pragma unroll
      for (int j = 0; j < 4; j++)
        acc[i][j] = mfma16(av[i], bv[j], acc[i][j]);
    __builtin_amdgcn_s_setprio(0);
  }
#undef GSTAGE

#pragma unroll
  for (int j2 = 0; j2 < 4; j2++) {
    int col = n0 + wn * 64 + j2 * 16 + lr;
    float bv_ = bias[col];
#pragma unroll
    for (int i = 0; i < 4; i++) {
      int row = m0 + wm * 64 + i * 16 + lg * 4;
#pragma unroll
      for (int r = 0; r < 4; r++) {
        float v = acc[i][j2][r] + bv_;
        if (OUT_BF16)
          ((unsigned short*)Cout)[(size_t)(row + r) * N + col] = f2bf(v);
        else
          ((float*)Cout)[(size_t)(row + r) * N + col] = v;
      }
    }
  }
}

// ---------- per-head V transpose: qkv[b][t][2048+h*64+d] -> vt[bh][d][t] ----------
__global__ void k_vt(const unsigned short* __restrict__ qkv, unsigned short* __restrict__ vt) {
  __shared__ unsigned short tile[64][65];
  int bh = blockIdx.y, t0 = blockIdx.x * 64;
  int b = bh >> 4, h = bh & 15;
  int tx = threadIdx.x, ty = threadIdx.y;  // (64,4)
  const unsigned short* src = qkv + (size_t)(b * TT + t0) * N3 + 2 * CC + h * HSS;
  for (int r = ty; r < 64; r += 4)
    tile[r][tx] = src[(size_t)r * N3 + tx];
  __syncthreads();
  unsigned short* dst = vt + (size_t)bh * HSS * TT + t0;
  for (int r = ty; r < 64; r += 4)
    dst[(size_t)r * TT + tx] = tile[tx][r];
}

// ---------- flash attention: 8 waves, kv-parity split, paired q-tiles ----------
// (round-9 version, proven 42us) 256 blocks x 8 waves. Block = (bh, p):
// segment A = q-tile 15-p, then B = p. Wave = (qsub 0..3, par 0..1). Ring-3
// K/V LDS, depth-1 prefetch + counted vmcnt(4). Parity merge through Ps.
__global__ __launch_bounds__(512) void k_attn(const unsigned short* __restrict__ qkv,
                                              const unsigned short* __restrict__ vt,
                                              unsigned short* __restrict__ y) {
  __shared__ __align__(16) unsigned short Ks[3][128 * 64];
  __shared__ __align__(16) unsigned short Vs[3][128 * 64];
  __shared__ __align__(16) unsigned short Ps[8][32 * 64];
  __shared__ float Msh[4][64];
  __shared__ float Lsh[4][64];
  const int t = threadIdx.x;
  const int w = t >> 6, l = t & 63, lq = l & 31, hl = l >> 5;
  const int qsub = w & 3, par = w >> 2;
  const int id = blockIdx.x;
  const int bh = (id & 7) + 8 * ((id >> 3) & 3);
  const int p = id >> 5;  // 0..7
  const int b = bh >> 4, head = bh & 15;
  const int jA = 15 - p, jB = p;
  const int mA = jA + 1;        // + (jB+1) = 17 macro-steps
  const int NT = 17;
  const float cexp = 0.18033688011112042f;  // (1/8)*log2(e)
  const float THR = 40.0f;

#define SWZ(r_) ((((r_) & 7) ^ (((r_) >> 3) & 3)) << 4)

  const int myswz = SWZ(lq);
  int offs[4];
#pragma unroll
  for (int s = 0; s < 4; s++) offs[s] = (32 * s + 16 * hl) ^ myswz;

  // staging: two glds16 issues per array; linear LDS off = i*8192 + w*1024 + l*16
  const int off0 = w * 1024 + l * 16;
  const int off1 = 8192 + w * 1024 + l * 16;
  const int rk0 = off0 >> 7, rk1 = off1 >> 7;          // K rows 0..127
  const int ck0 = (off0 & 127) ^ SWZ(rk0), ck1 = (off1 & 127) ^ SWZ(rk1);
  const int rv0 = rk0 & 63, rv1 = rk1 & 63;            // V rows 0..63, subtile = i
  const int cv0 = (off0 & 127) ^ SWZ(rv0), cv1 = (off1 & 127) ^ SWZ(rv1);
  const char* gK0 = (const char*)(qkv + (size_t)(b * TT + rk0) * N3 + CC + head * HSS) + ck0;
  const char* gK1 = (const char*)(qkv + (size_t)(b * TT + rk1) * N3 + CC + head * HSS) + ck1;
  const char* gV0 = (const char*)(vt + ((size_t)bh * HSS + rv0) * TT) + cv0;        // kv 0..63
  const char* gV1 = (const char*)(vt + ((size_t)bh * HSS + rv1) * TT + 64) + cv1;   // kv 64..127
  const int dK0 = w * 1024, dK1 = 8192 + w * 1024;

#define STAGE(slot_, kvt_)                                                \
  do {                                                                    \
    size_t kb = (size_t)(kvt_) * (128 * N3 * 2);                          \
    size_t vb = (size_t)(kvt_) * 256;                                     \
    glds16(gK0 + kb, (char*)Ks[slot_] + dK0);                             \
    glds16(gK1 + kb, (char*)Ks[slot_] + dK1);                             \
    glds16(gV0 + vb, (char*)Vs[slot_] + dK0);                             \
    glds16(gV1 + vb, (char*)Vs[slot_] + dK1);                             \
  } while (0)

#define WRITE_OUT()                                                       \
  do {                                                                    \
    float l_q = l_ln + __shfl_xor(l_ln, 32);                              \
    float inv = 1.0f / l_q;                                               \
    unsigned short* ybase = y + (size_t)(b * TT + q0w + lq) * CC + head * HSS; \
    _Pragma("unroll")                                                     \
    for (int g = 0; g < 4; g++) {                                         \
      ushort4 wv;                                                         \
      wv.x = f2bf(oa[4 * g + 0] * inv); wv.y = f2bf(oa[4 * g + 1] * inv); \
      wv.z = f2bf(oa[4 * g + 2] * inv); wv.w = f2bf(oa[4 * g + 3] * inv); \
      *(ushort4*)(ybase + 8 * g + 4 * hl) = wv;                           \
      ushort4 wv2;                                                        \
      wv2.x = f2bf(ob[4 * g + 0] * inv); wv2.y = f2bf(ob[4 * g + 1] * inv); \
      wv2.z = f2bf(ob[4 * g + 2] * inv); wv2.w = f2bf(ob[4 * g + 3] * inv); \
      *(ushort4*)(ybase + 32 + 8 * g + 4 * hl) = wv2;                     \
    }                                                                     \
  } while (0)

// cross-parity merge: par1 writes (oa,ob,m,l) through Ps; par0 combines + stores y
#define MERGE()                                                           \
  do {                                                                    \
    __builtin_amdgcn_s_barrier();                                         \
    if (par) {                                                            \
      float* poa = (float*)Ps[w];                                         \
      float* pob = (float*)Ps[w - 4];                                     \
      _Pragma("unroll")                                                   \
      for (int g = 0; g < 16; g++) { poa[g * 64 + l] = oa[g]; pob[g * 64 + l] = ob[g]; } \
      Msh[qsub][l] = m_s; Lsh[qsub][l] = l_ln;                            \
    }                                                                     \
    asm volatile("s_waitcnt lgkmcnt(0)" ::: "memory");                    \
    __builtin_amdgcn_s_barrier();                                         \
    __builtin_amdgcn_sched_barrier(0);                                    \
    if (!par) {                                                           \
      float m1 = Msh[qsub][l], l1 = Lsh[qsub][l];                         \
      float mstar = fmaxf(m_s, m1);                                       \
      float a0 = __builtin_amdgcn_exp2f((m_s - mstar) * cexp);            \
      float a1 = __builtin_amdgcn_exp2f((m1 - mstar) * cexp);             \
      const float* poa = (const float*)Ps[w + 4];                         \
      const float* pob = (const float*)Ps[w];                             \
      _Pragma("unroll")                                                   \
      for (int g = 0; g < 16; g++) {                                      \
        oa[g] = oa[g] * a0 + poa[g * 64 + l] * a1;                        \
        ob[g] = ob[g] * a0 + pob[g * 64 + l] * a1;                        \
      }                                                                   \
      l_ln = l_ln * a0 + l1 * a1;                                         \
      WRITE_OUT();                                                        \
    }                                                                     \
    __builtin_amdgcn_s_barrier();                                         \
  } while (0)

  // segment A state
  int q0w = jA * 128 + qsub * 32;
  const unsigned short* qp = qkv + (size_t)(b * TT + q0w + lq) * N3 + head * HSS + hl * 8;
  bf16x8 qf0 = ld8(qp), qf1 = ld8(qp + 16), qf2 = ld8(qp + 32), qf3 = ld8(qp + 48);
  float m_s = -INFINITY, l_ln = 0.f;
  f32x16 oa = z16(), ob = z16();
  char* prow = (char*)Ps[w] + lq * 128;

  STAGE(0, 0);
  int cur = 0;

  for (int seq = 0; seq < NT; ++seq) {
    if (seq == mA) {
      MERGE();  // finalize segment A; y written by par0
      q0w = jB * 128 + qsub * 32;
      const unsigned short* qp2 = qkv + (size_t)(b * TT + q0w + lq) * N3 + head * HSS + hl * 8;
      qf0 = ld8(qp2); qf1 = ld8(qp2 + 16); qf2 = ld8(qp2 + 32); qf3 = ld8(qp2 + 48);
      m_s = -INFINITY; l_ln = 0.f;
      oa = z16(); ob = z16();
    }

    const int kvt = (seq < mA) ? seq : (seq - mA);
    if (seq + 1 < NT) {
      int s2 = seq + 1;
      int kvt2 = (s2 < mA) ? s2 : (s2 - mA);
      int nxt = (cur == 2) ? 0 : cur + 1;
      STAGE(nxt, kvt2);
      __builtin_amdgcn_sched_barrier(0);
      asm volatile("s_waitcnt vmcnt(4)" ::: "memory");
    } else {
      asm volatile("s_waitcnt vmcnt(0)" ::: "memory");
    }
    __builtin_amdgcn_s_barrier();
    __builtin_amdgcn_sched_barrier(0);

    const int mybuf = cur;
    cur = (cur == 2) ? 0 : cur + 1;

    const int kv0w = kvt * 128 + 64 * par;
    if (kv0w > q0w + 31) continue;  // fully-masked for this wave (barriers done)

    const unsigned short* Kb = Ks[mybuf];
    const unsigned short* Vb = Vs[mybuf];

    // QK^T swapped: sa/sb hold S^T[kv][q=lq], kv=kv0w+(g&3)+8*(g>>2)+4*hl (+32 sb)
    const char* krA = (const char*)Kb + (64 * par + lq) * 128;
    const char* krB = krA + 32 * 128;
    f32x16 sa = z16(), sb = z16();
    __builtin_amdgcn_s_setprio(1);
    {
      bf16x8 ka, kb8;
      ka = ld8((const unsigned short*)(krA + offs[0]));
      kb8 = ld8((const unsigned short*)(krB + offs[0]));
      sa = mfma32(ka, qf0, sa); sb = mfma32(kb8, qf0, sb);
      ka = ld8((const unsigned short*)(krA + offs[1]));
      kb8 = ld8((const unsigned short*)(krB + offs[1]));
      sa = mfma32(ka, qf1, sa); sb = mfma32(kb8, qf1, sb);
      ka = ld8((const unsigned short*)(krA + offs[2]));
      kb8 = ld8((const unsigned short*)(krB + offs[2]));
      sa = mfma32(ka, qf2, sa); sb = mfma32(kb8, qf2, sb);
      ka = ld8((const unsigned short*)(krA + offs[3]));
      kb8 = ld8((const unsigned short*)(krB + offs[3]));
      sa = mfma32(ka, qf3, sa); sb = mfma32(kb8, qf3, sb);
    }
    __builtin_amdgcn_s_setprio(0);

    // causal mask near the diagonal
    if (kv0w + 63 > q0w) {
      const int q = q0w + lq;
#pragma unroll
      for (int g = 0; g < 16; g++) {
        int kvl = kv0w + (g & 3) + 8 * (g >> 2) + 4 * hl;
        if (kvl > q) sa[g] = -INFINITY;
        if (kvl + 32 > q) sb[g] = -INFINITY;
      }
    }

    // per-lane max + cross-half combine
    float tmax = -INFINITY;
#pragma unroll
    for (int g = 0; g < 16; g++) tmax = fmaxf(tmax, fmaxf(sa[g], sb[g]));
    tmax = fmaxf(tmax, __shfl_xor(tmax, 32));

    if (!__all(tmax <= m_s + THR)) {
      float m_new = fmaxf(m_s, tmax);
      float alpha = __builtin_amdgcn_exp2f((m_s - m_new) * cexp);
      l_ln *= alpha;
#pragma unroll
      for (int g = 0; g < 16; g++) { oa[g] *= alpha; ob[g] *= alpha; }
      m_s = m_new;
    }

    // exp in place; accumulate per-lane l
    const float mc = m_s * cexp;
    float tsum = 0.f;
#pragma unroll
    for (int g = 0; g < 16; g++) {
      sa[g] = __builtin_amdgcn_exp2f(__builtin_fmaf(sa[g], cexp, -mc));
      sb[g] = __builtin_amdgcn_exp2f(__builtin_fmaf(sb[g], cexp, -mc));
      tsum += sa[g] + sb[g];
    }
    l_ln += tsum;

    // P -> LDS bounce (wave-private)
#pragma unroll
    for (int u2 = 0; u2 < 4; u2++) {
      bf16x4 w0, w1;
#pragma unroll
      for (int r = 0; r < 4; r++) { w0[r] = (__bf16)sa[4 * u2 + r]; w1[r] = (__bf16)sb[4 * u2 + r]; }
      *(bf16x4*)(prow + ((16 * u2 + 8 * hl) ^ myswz)) = w0;
      *(bf16x4*)(prow + ((64 + 16 * u2 + 8 * hl) ^ myswz)) = w1;
    }
    asm volatile("s_waitcnt lgkmcnt(0)" ::: "memory");
    __builtin_amdgcn_sched_barrier(0);
    bf16x8 pf0 = ld8((const unsigned short*)(prow + offs[0]));
    bf16x8 pf1 = ld8((const unsigned short*)(prow + offs[1]));
    bf16x8 pf2 = ld8((const unsigned short*)(prow + offs[2]));
    bf16x8 pf3 = ld8((const unsigned short*)(prow + offs[3]));

    // PV on this wave's V subtile (kv parity half)
    const char* vrA = (const char*)Vb + par * 8192 + lq * 128;
    const char* vrB = vrA + 32 * 128;
    __builtin_amdgcn_s_setprio(1);
    {
      bf16x8 va, vb8;
      va = ld8((const unsigned short*)(vrA + offs[0]));
      vb8 = ld8((const unsigned short*)(vrB + offs[0]));
      oa = mfma32(va, pf0, oa); ob = mfma32(vb8, pf0, ob);
      va = ld8((const unsigned short*)(vrA + offs[1]));
      vb8 = ld8((const unsigned short*)(vrB + offs[1]));
      oa = mfma32(va, pf1, oa); ob = mfma32(vb8, pf1, ob);
      va = ld8((const unsigned short*)(vrA + offs[2]));
      vb8 = ld8((const unsigned short*)(vrB + offs[2]));
      oa = mfma32(va, pf2, oa); ob = mfma32(vb8, pf2, ob);
      va = ld8((const unsigned short*)(vrA + offs[3]));
      vb8 = ld8((const unsigned short*)(vrB + offs[3]));
      oa = mfma32(va, pf3, oa); ob = mfma32(vb8, pf3, ob);
    }
    __builtin_amdgcn_s_setprio(0);
  }

  MERGE();  // finalize segment B
#undef STAGE
#undef WRITE_OUT
#undef MERGE
#undef SWZ
}

extern "C" void kernel_launch(void* const* d_in, const int* in_sizes, int n_in,
                              void* d_out, int out_size, void* d_ws, size_t ws_size,
                              hipStream_t stream) {
  const float* x = (const float*)d_in[0];
  const float* W_attn = (const float*)d_in[1];
  const float* b_attn = (const float*)d_in[2];
  const float* W_proj = (const float*)d_in[3];
  const float* b_proj = (const float*)d_in[4];

  char* ws = (char*)d_ws;
  unsigned short* xb   = (unsigned short*)(ws);                       // 8 MB
  unsigned short* wabt = (unsigned short*)(ws + 8388608);             // 6 MB  [3072][1024]
  unsigned short* wpbt = (unsigned short*)(ws + 14680064);            // 2 MB  [1024][1024]
  unsigned short* qkvb = (unsigned short*)(ws + 16777216);            // 24 MB [4096][3072]
  unsigned short* vt   = (unsigned short*)(ws + 41943040);            // 8 MB  [32][64][2048]
  unsigned short* yb   = (unsigned short*)(ws + 50331648);            // 8 MB  [4096][1024]

  k_conv<<<2048, 256, 0, stream>>>(x, xb, BT * CC / 4);
  k_transp<<<dim3(N3 / 32, CC / 32), dim3(32, 8), 0, stream>>>(W_attn, wabt, CC, N3);
  k_transp<<<dim3(CC / 32, CC / 32), dim3(32, 8), 0, stream>>>(W_proj, wpbt, CC, CC);
  // QKV: M=4096, N=3072 -> 32x24 = 768 blocks (768 % 8 == 0)
  k_gemm<1><<<dim3(768), 256, 0, stream>>>(xb, wabt, b_attn, qkvb, N3, CC, 24);
  k_vt<<<dim3(TT / 64, BB * NHH), dim3(64, 4), 0, stream>>>(qkvb, vt);
  k_attn<<<dim3(256), 512, 0, stream>>>(qkvb, vt, yb);
  // proj: M=4096, N=1024 -> 32x8 = 256 blocks (256 % 8 == 0)
  k_gemm<0><<<dim3(256), 256, 0, stream>>>(yb, wpbt, b_proj, d_out, CC, CC, 8);
}

// Round 13
// 115.883 us; speedup vs baseline: 1.0638x; 1.0027x over previous
//
#include <hip/hip_runtime.h>
#include <hip/hip_bf16.h>
#include <stdint.h>

#define DEV static __device__ __forceinline__

typedef __attribute__((ext_vector_type(8))) __bf16 bf16x8;
typedef __attribute__((ext_vector_type(4))) __bf16 bf16x4;
typedef __attribute__((ext_vector_type(4))) float f32x4;
typedef __attribute__((ext_vector_type(16))) float f32x16;

// B=2, T=2048, C=1024, NH=16, HS=64
#define BB 2
#define TT 2048
#define CC 1024
#define NHH 16
#define HSS 64
#define BT 4096
#define N3 3072

DEV unsigned short f2bf(float f) {
  union { float f; uint32_t u; } v; v.f = f;
  uint32_t r = v.u + 0x7FFFu + ((v.u >> 16) & 1u);
  return (unsigned short)(r >> 16);
}

typedef const __attribute__((address_space(1))) unsigned int* gas_t;
typedef __attribute__((address_space(3))) unsigned int* las_t;

DEV void glds16(const void* g, void* l) {
  __builtin_amdgcn_global_load_lds((gas_t)g, (las_t)l, 16, 0, 0);
}

DEV f32x4 mfma16(bf16x8 a, bf16x8 b, f32x4 c) {
  return __builtin_amdgcn_mfma_f32_16x16x32_bf16(a, b, c, 0, 0, 0);
}
DEV f32x16 mfma32(bf16x8 a, bf16x8 b, f32x16 c) {
  return __builtin_amdgcn_mfma_f32_32x32x16_bf16(a, b, c, 0, 0, 0);
}

DEV bf16x8 ld8(const unsigned short* p) { return *(const bf16x8*)p; }

DEV f32x16 z16() {
  f32x16 v;
#pragma unroll
  for (int i = 0; i < 16; i++) v[i] = 0.f;
  return v;
}

// ---------- fp32 -> bf16 convert (vectorized) ----------
__global__ void k_conv(const float* __restrict__ in, unsigned short* __restrict__ out, int n4) {
  int i = blockIdx.x * blockDim.x + threadIdx.x;
  int stride = gridDim.x * blockDim.x;
  for (; i < n4; i += stride) {
    float4 v = ((const float4*)in)[i];
    ushort4 o;
    o.x = f2bf(v.x); o.y = f2bf(v.y); o.z = f2bf(v.z); o.w = f2bf(v.w);
    ((ushort4*)out)[i] = o;
  }
}

// ---------- transpose+convert: in [K][N] f32 -> out [N][K] bf16 ----------
__global__ void k_transp(const float* __restrict__ in, unsigned short* __restrict__ out,
                         int K, int N) {
  __shared__ float tile[32][33];
  int n0 = blockIdx.x * 32, k0 = blockIdx.y * 32;
  int tx = threadIdx.x, ty = threadIdx.y;  // (32,8)
  for (int r = ty; r < 32; r += 8)
    tile[r][tx] = in[(size_t)(k0 + r) * N + n0 + tx];
  __syncthreads();
  for (int r = ty; r < 32; r += 8)
    out[(size_t)(n0 + r) * K + k0 + tx] = f2bf(tile[tx][r]);
}

// ---------- GEMM: A[M][K] bf16, Bt[N][K] bf16, bias f32[N] ----------
// 128x128 tile, BK=32, 8 waves (2M x 4N, 64x32 per wave), ring-3 LDS (48KB),
// depth-2 prefetch + counted vmcnt (stage = 2 glds16 -> 4/2/0). Two
// non-draining barriers per step. XCD-chunked bijective block swizzle.
template <int OUT_BF16>
__global__ __launch_bounds__(512) void k_gemm(const unsigned short* __restrict__ A,
                                              const unsigned short* __restrict__ Bt,
                                              const float* __restrict__ bias,
                                              void* __restrict__ Cout,
                                              int N, int K, int gx) {
  __shared__ __align__(16) unsigned short As[3][128 * 32];
  __shared__ __align__(16) unsigned short Bs[3][128 * 32];
  const int t = threadIdx.x;
  const int wave = t >> 6, l = t & 63, lr = l & 15, lg = l >> 4;
  const int cpx = gridDim.x >> 3;
  const int sw = ((int)blockIdx.x & 7) * cpx + ((int)blockIdx.x >> 3);
  const int m0 = (sw / gx) * 128, n0 = (sw % gx) * 128;
  const int wm = wave >> 2, wn = wave & 3;

  f32x4 acc[4][2] = {};

  // staging map: thread t -> row t>>2 (0..127), chunk (t&3)*16B; one issue/array
  const unsigned short* gA = A + (size_t)(m0 + (t >> 2)) * K + (t & 3) * 8;
  const unsigned short* gB = Bt + (size_t)(n0 + (t >> 2)) * K + (t & 3) * 8;

#define GSTAGE(buf_, k_)                                                  \
  do {                                                                    \
    glds16(gA + (k_), (char*)As[buf_] + t * 16);                          \
    glds16(gB + (k_), (char*)Bs[buf_] + t * 16);                          \
  } while (0)

  const int nst = K >> 5;
  GSTAGE(0, 0);
  GSTAGE(1, 32);

  for (int st = 0; st < nst; ++st) {
    __builtin_amdgcn_s_barrier();          // A: guards slot (st+2)%3 overwrite
    __builtin_amdgcn_sched_barrier(0);
    if (st + 2 < nst) GSTAGE((st + 2) % 3, (st + 2) * 32);
    __builtin_amdgcn_sched_barrier(0);
    if (st + 2 < nst)      asm volatile("s_waitcnt vmcnt(4)" ::: "memory");
    else if (st + 1 < nst) asm volatile("s_waitcnt vmcnt(2)" ::: "memory");
    else                   asm volatile("s_waitcnt vmcnt(0)" ::: "memory");
    __builtin_amdgcn_s_barrier();          // B: all waves' stage(st) visible
    __builtin_amdgcn_sched_barrier(0);

    const unsigned short* Ab = As[st % 3];
    const unsigned short* Bb = Bs[st % 3];
    bf16x8 av[4], bv[2];
#pragma unroll
    for (int i = 0; i < 4; i++)
      av[i] = ld8(Ab + (wm * 64 + i * 16 + lr) * 32 + lg * 8);
#pragma unroll
    for (int j = 0; j < 2; j++)
      bv[j] = ld8(Bb + (wn * 32 + j * 16 + lr) * 32 + lg * 8);
    __builtin_amdgcn_s_setprio(1);
#pragma unroll
    for (int i = 0; i < 4; i++)
#pragma unroll
      for (int j = 0; j < 2; j++)
        acc[i][j] = mfma16(av[i], bv[j], acc[i][j]);
    __builtin_amdgcn_s_setprio(0);
  }
#undef GSTAGE

#pragma unroll
  for (int j2 = 0; j2 < 2; j2++) {
    int col = n0 + wn * 32 + j2 * 16 + lr;
    float bv_ = bias[col];
#pragma unroll
    for (int i = 0; i < 4; i++) {
      int row = m0 + wm * 64 + i * 16 + lg * 4;
#pragma unroll
      for (int r = 0; r < 4; r++) {
        float v = acc[i][j2][r] + bv_;
        if (OUT_BF16)
          ((unsigned short*)Cout)[(size_t)(row + r) * N + col] = f2bf(v);
        else
          ((float*)Cout)[(size_t)(row + r) * N + col] = v;
      }
    }
  }
}

// ---------- per-head V transpose: qkv[b][t][2048+h*64+d] -> vt[bh][d][t] ----------
__global__ void k_vt(const unsigned short* __restrict__ qkv, unsigned short* __restrict__ vt) {
  __shared__ unsigned short tile[64][65];
  int bh = blockIdx.y, t0 = blockIdx.x * 64;
  int b = bh >> 4, h = bh & 15;
  int tx = threadIdx.x, ty = threadIdx.y;  // (64,4)
  const unsigned short* src = qkv + (size_t)(b * TT + t0) * N3 + 2 * CC + h * HSS;
  for (int r = ty; r < 64; r += 4)
    tile[r][tx] = src[(size_t)r * N3 + tx];
  __syncthreads();
  unsigned short* dst = vt + (size_t)bh * HSS * TT + t0;
  for (int r = ty; r < 64; r += 4)
    dst[(size_t)r * TT + tx] = tile[tx][r];
}

// ---------- flash attention: 8 waves, kv-parity split, paired q-tiles ----------
// (round-9 version, proven 42us) 256 blocks x 8 waves. Block = (bh, p):
// segment A = q-tile 15-p, then B = p. Wave = (qsub 0..3, par 0..1). Ring-3
// K/V LDS, depth-1 prefetch + counted vmcnt(4). Parity merge through Ps.
__global__ __launch_bounds__(512) void k_attn(const unsigned short* __restrict__ qkv,
                                              const unsigned short* __restrict__ vt,
                                              unsigned short* __restrict__ y) {
  __shared__ __align__(16) unsigned short Ks[3][128 * 64];
  __shared__ __align__(16) unsigned short Vs[3][128 * 64];
  __shared__ __align__(16) unsigned short Ps[8][32 * 64];
  __shared__ float Msh[4][64];
  __shared__ float Lsh[4][64];
  const int t = threadIdx.x;
  const int w = t >> 6, l = t & 63, lq = l & 31, hl = l >> 5;
  const int qsub = w & 3, par = w >> 2;
  const int id = blockIdx.x;
  const int bh = (id & 7) + 8 * ((id >> 3) & 3);
  const int p = id >> 5;  // 0..7
  const int b = bh >> 4, head = bh & 15;
  const int jA = 15 - p, jB = p;
  const int mA = jA + 1;        // + (jB+1) = 17 macro-steps
  const int NT = 17;
  const float cexp = 0.18033688011112042f;  // (1/8)*log2(e)
  const float THR = 40.0f;

#define SWZ(r_) ((((r_) & 7) ^ (((r_) >> 3) & 3)) << 4)

  const int myswz = SWZ(lq);
  int offs[4];
#pragma unroll
  for (int s = 0; s < 4; s++) offs[s] = (32 * s + 16 * hl) ^ myswz;

  // staging: two glds16 issues per array; linear LDS off = i*8192 + w*1024 + l*16
  const int off0 = w * 1024 + l * 16;
  const int off1 = 8192 + w * 1024 + l * 16;
  const int rk0 = off0 >> 7, rk1 = off1 >> 7;          // K rows 0..127
  const int ck0 = (off0 & 127) ^ SWZ(rk0), ck1 = (off1 & 127) ^ SWZ(rk1);
  const int rv0 = rk0 & 63, rv1 = rk1 & 63;            // V rows 0..63, subtile = i
  const int cv0 = (off0 & 127) ^ SWZ(rv0), cv1 = (off1 & 127) ^ SWZ(rv1);
  const char* gK0 = (const char*)(qkv + (size_t)(b * TT + rk0) * N3 + CC + head * HSS) + ck0;
  const char* gK1 = (const char*)(qkv + (size_t)(b * TT + rk1) * N3 + CC + head * HSS) + ck1;
  const char* gV0 = (const char*)(vt + ((size_t)bh * HSS + rv0) * TT) + cv0;        // kv 0..63
  const char* gV1 = (const char*)(vt + ((size_t)bh * HSS + rv1) * TT + 64) + cv1;   // kv 64..127
  const int dK0 = w * 1024, dK1 = 8192 + w * 1024;

#define STAGE(slot_, kvt_)                                                \
  do {                                                                    \
    size_t kb = (size_t)(kvt_) * (128 * N3 * 2);                          \
    size_t vb = (size_t)(kvt_) * 256;                                     \
    glds16(gK0 + kb, (char*)Ks[slot_] + dK0);                             \
    glds16(gK1 + kb, (char*)Ks[slot_] + dK1);                             \
    glds16(gV0 + vb, (char*)Vs[slot_] + dK0);                             \
    glds16(gV1 + vb, (char*)Vs[slot_] + dK1);                             \
  } while (0)

#define WRITE_OUT()                                                       \
  do {                                                                    \
    float l_q = l_ln + __shfl_xor(l_ln, 32);                              \
    float inv = 1.0f / l_q;                                               \
    unsigned short* ybase = y + (size_t)(b * TT + q0w + lq) * CC + head * HSS; \
    _Pragma("unroll")                                                     \
    for (int g = 0; g < 4; g++) {                                         \
      ushort4 wv;                                                         \
      wv.x = f2bf(oa[4 * g + 0] * inv); wv.y = f2bf(oa[4 * g + 1] * inv); \
      wv.z = f2bf(oa[4 * g + 2] * inv); wv.w = f2bf(oa[4 * g + 3] * inv); \
      *(ushort4*)(ybase + 8 * g + 4 * hl) = wv;                           \
      ushort4 wv2;                                                        \
      wv2.x = f2bf(ob[4 * g + 0] * inv); wv2.y = f2bf(ob[4 * g + 1] * inv); \
      wv2.z = f2bf(ob[4 * g + 2] * inv); wv2.w = f2bf(ob[4 * g + 3] * inv); \
      *(ushort4*)(ybase + 32 + 8 * g + 4 * hl) = wv2;                     \
    }                                                                     \
  } while (0)

// cross-parity merge: par1 writes (oa,ob,m,l) through Ps; par0 combines + stores y
#define MERGE()                                                           \
  do {                                                                    \
    __builtin_amdgcn_s_barrier();                                         \
    if (par) {                                                            \
      float* poa = (float*)Ps[w];                                         \
      float* pob = (float*)Ps[w - 4];                                     \
      _Pragma("unroll")                                                   \
      for (int g = 0; g < 16; g++) { poa[g * 64 + l] = oa[g]; pob[g * 64 + l] = ob[g]; } \
      Msh[qsub][l] = m_s; Lsh[qsub][l] = l_ln;                            \
    }                                                                     \
    asm volatile("s_waitcnt lgkmcnt(0)" ::: "memory");                    \
    __builtin_amdgcn_s_barrier();                                         \
    __builtin_amdgcn_sched_barrier(0);                                    \
    if (!par) {                                                           \
      float m1 = Msh[qsub][l], l1 = Lsh[qsub][l];                         \
      float mstar = fmaxf(m_s, m1);                                       \
      float a0 = __builtin_amdgcn_exp2f((m_s - mstar) * cexp);            \
      float a1 = __builtin_amdgcn_exp2f((m1 - mstar) * cexp);             \
      const float* poa = (const float*)Ps[w + 4];                         \
      const float* pob = (const float*)Ps[w];                             \
      _Pragma("unroll")                                                   \
      for (int g = 0; g < 16; g++) {                                      \
        oa[g] = oa[g] * a0 + poa[g * 64 + l] * a1;                        \
        ob[g] = ob[g] * a0 + pob[g * 64 + l] * a1;                        \
      }                                                                   \
      l_ln = l_ln * a0 + l1 * a1;                                         \
      WRITE_OUT();                                                        \
    }                                                                     \
    __builtin_amdgcn_s_barrier();                                         \
  } while (0)

  // segment A state
  int q0w = jA * 128 + qsub * 32;
  const unsigned short* qp = qkv + (size_t)(b * TT + q0w + lq) * N3 + head * HSS + hl * 8;
  bf16x8 qf0 = ld8(qp), qf1 = ld8(qp + 16), qf2 = ld8(qp + 32), qf3 = ld8(qp + 48);
  float m_s = -INFINITY, l_ln = 0.f;
  f32x16 oa = z16(), ob = z16();
  char* prow = (char*)Ps[w] + lq * 128;

  STAGE(0, 0);
  int cur = 0;

  for (int seq = 0; seq < NT; ++seq) {
    if (seq == mA) {
      MERGE();  // finalize segment A; y written by par0
      q0w = jB * 128 + qsub * 32;
      const unsigned short* qp2 = qkv + (size_t)(b * TT + q0w + lq) * N3 + head * HSS + hl * 8;
      qf0 = ld8(qp2); qf1 = ld8(qp2 + 16); qf2 = ld8(qp2 + 32); qf3 = ld8(qp2 + 48);
      m_s = -INFINITY; l_ln = 0.f;
      oa = z16(); ob = z16();
    }

    const int kvt = (seq < mA) ? seq : (seq - mA);
    if (seq + 1 < NT) {
      int s2 = seq + 1;
      int kvt2 = (s2 < mA) ? s2 : (s2 - mA);
      int nxt = (cur == 2) ? 0 : cur + 1;
      STAGE(nxt, kvt2);
      __builtin_amdgcn_sched_barrier(0);
      asm volatile("s_waitcnt vmcnt(4)" ::: "memory");
    } else {
      asm volatile("s_waitcnt vmcnt(0)" ::: "memory");
    }
    __builtin_amdgcn_s_barrier();
    __builtin_amdgcn_sched_barrier(0);

    const int mybuf = cur;
    cur = (cur == 2) ? 0 : cur + 1;

    const int kv0w = kvt * 128 + 64 * par;
    if (kv0w > q0w + 31) continue;  // fully-masked for this wave (barriers done)

    const unsigned short* Kb = Ks[mybuf];
    const unsigned short* Vb = Vs[mybuf];

    // QK^T swapped: sa/sb hold S^T[kv][q=lq], kv=kv0w+(g&3)+8*(g>>2)+4*hl (+32 sb)
    const char* krA = (const char*)Kb + (64 * par + lq) * 128;
    const char* krB = krA + 32 * 128;
    f32x16 sa = z16(), sb = z16();
    __builtin_amdgcn_s_setprio(1);
    {
      bf16x8 ka, kb8;
      ka = ld8((const unsigned short*)(krA + offs[0]));
      kb8 = ld8((const unsigned short*)(krB + offs[0]));
      sa = mfma32(ka, qf0, sa); sb = mfma32(kb8, qf0, sb);
      ka = ld8((const unsigned short*)(krA + offs[1]));
      kb8 = ld8((const unsigned short*)(krB + offs[1]));
      sa = mfma32(ka, qf1, sa); sb = mfma32(kb8, qf1, sb);
      ka = ld8((const unsigned short*)(krA + offs[2]));
      kb8 = ld8((const unsigned short*)(krB + offs[2]));
      sa = mfma32(ka, qf2, sa); sb = mfma32(kb8, qf2, sb);
      ka = ld8((const unsigned short*)(krA + offs[3]));
      kb8 = ld8((const unsigned short*)(krB + offs[3]));
      sa = mfma32(ka, qf3, sa); sb = mfma32(kb8, qf3, sb);
    }
    __builtin_amdgcn_s_setprio(0);

    // causal mask near the diagonal
    if (kv0w + 63 > q0w) {
      const int q = q0w + lq;
#pragma unroll
      for (int g = 0; g < 16; g++) {
        int kvl = kv0w + (g & 3) + 8 * (g >> 2) + 4 * hl;
        if (kvl > q) sa[g] = -INFINITY;
        if (kvl + 32 > q) sb[g] = -INFINITY;
      }
    }

    // per-lane max + cross-half combine
    float tmax = -INFINITY;
#pragma unroll
    for (int g = 0; g < 16; g++) tmax = fmaxf(tmax, fmaxf(sa[g], sb[g]));
    tmax = fmaxf(tmax, __shfl_xor(tmax, 32));

    if (!__all(tmax <= m_s + THR)) {
      float m_new = fmaxf(m_s, tmax);
      float alpha = __builtin_amdgcn_exp2f((m_s - m_new) * cexp);
      l_ln *= alpha;
#pragma unroll
      for (int g = 0; g < 16; g++) { oa[g] *= alpha; ob[g] *= alpha; }
      m_s = m_new;
    }

    // exp in place; accumulate per-lane l
    const float mc = m_s * cexp;
    float tsum = 0.f;
#pragma unroll
    for (int g = 0; g < 16; g++) {
      sa[g] = __builtin_amdgcn_exp2f(__builtin_fmaf(sa[g], cexp, -mc));
      sb[g] = __builtin_amdgcn_exp2f(__builtin_fmaf(sb[g], cexp, -mc));
      tsum += sa[g] + sb[g];
    }
    l_ln += tsum;

    // P -> LDS bounce (wave-private)
#pragma unroll
    for (int u2 = 0; u2 < 4; u2++) {
      bf16x4 w0, w1;
#pragma unroll
      for (int r = 0; r < 4; r++) { w0[r] = (__bf16)sa[4 * u2 + r]; w1[r] = (__bf16)sb[4 * u2 + r]; }
      *(bf16x4*)(prow + ((16 * u2 + 8 * hl) ^ myswz)) = w0;
      *(bf16x4*)(prow + ((64 + 16 * u2 + 8 * hl) ^ myswz)) = w1;
    }
    asm volatile("s_waitcnt lgkmcnt(0)" ::: "memory");
    __builtin_amdgcn_sched_barrier(0);
    bf16x8 pf0 = ld8((const unsigned short*)(prow + offs[0]));
    bf16x8 pf1 = ld8((const unsigned short*)(prow + offs[1]));
    bf16x8 pf2 = ld8((const unsigned short*)(prow + offs[2]));
    bf16x8 pf3 = ld8((const unsigned short*)(prow + offs[3]));

    // PV on this wave's V subtile (kv parity half)
    const char* vrA = (const char*)Vb + par * 8192 + lq * 128;
    const char* vrB = vrA + 32 * 128;
    __builtin_amdgcn_s_setprio(1);
    {
      bf16x8 va, vb8;
      va = ld8((const unsigned short*)(vrA + offs[0]));
      vb8 = ld8((const unsigned short*)(vrB + offs[0]));
      oa = mfma32(va, pf0, oa); ob = mfma32(vb8, pf0, ob);
      va = ld8((const unsigned short*)(vrA + offs[1]));
      vb8 = ld8((const unsigned short*)(vrB + offs[1]));
      oa = mfma32(va, pf1, oa); ob = mfma32(vb8, pf1, ob);
      va = ld8((const unsigned short*)(vrA + offs[2]));
      vb8 = ld8((const unsigned short*)(vrB + offs[2]));
      oa = mfma32(va, pf2, oa); ob = mfma32(vb8, pf2, ob);
      va = ld8((const unsigned short*)(vrA + offs[3]));
      vb8 = ld8((const unsigned short*)(vrB + offs[3]));
      oa = mfma32(va, pf3, oa); ob = mfma32(vb8, pf3, ob);
    }
    __builtin_amdgcn_s_setprio(0);
  }

  MERGE();  // finalize segment B
#undef STAGE
#undef WRITE_OUT
#undef MERGE
#undef SWZ
}

extern "C" void kernel_launch(void* const* d_in, const int* in_sizes, int n_in,
                              void* d_out, int out_size, void* d_ws, size_t ws_size,
                              hipStream_t stream) {
  const float* x = (const float*)d_in[0];
  const float* W_attn = (const float*)d_in[1];
  const float* b_attn = (const float*)d_in[2];
  const float* W_proj = (const float*)d_in[3];
  const float* b_proj = (const float*)d_in[4];

  char* ws = (char*)d_ws;
  unsigned short* xb   = (unsigned short*)(ws);                       // 8 MB
  unsigned short* wabt = (unsigned short*)(ws + 8388608);             // 6 MB  [3072][1024]
  unsigned short* wpbt = (unsigned short*)(ws + 14680064);            // 2 MB  [1024][1024]
  unsigned short* qkvb = (unsigned short*)(ws + 16777216);            // 24 MB [4096][3072]
  unsigned short* vt   = (unsigned short*)(ws + 41943040);            // 8 MB  [32][64][2048]
  unsigned short* yb   = (unsigned short*)(ws + 50331648);            // 8 MB  [4096][1024]

  k_conv<<<2048, 256, 0, stream>>>(x, xb, BT * CC / 4);
  k_transp<<<dim3(N3 / 32, CC / 32), dim3(32, 8), 0, stream>>>(W_attn, wabt, CC, N3);
  k_transp<<<dim3(CC / 32, CC / 32), dim3(32, 8), 0, stream>>>(W_proj, wpbt, CC, CC);
  // QKV: M=4096, N=3072 -> 32x24 = 768 blocks (768 % 8 == 0)
  k_gemm<1><<<dim3(768), 512, 0, stream>>>(xb, wabt, b_attn, qkvb, N3, CC, 24);
  k_vt<<<dim3(TT / 64, BB * NHH), dim3(64, 4), 0, stream>>>(qkvb, vt);
  k_attn<<<dim3(256), 512, 0, stream>>>(qkvb, vt, yb);
  // proj: M=4096, N=1024 -> 32x8 = 256 blocks (256 % 8 == 0)
  k_gemm<0><<<dim3(256), 512, 0, stream>>>(yb, wpbt, b_proj, d_out, CC, CC, 8);
}

// Round 14
// 109.716 us; speedup vs baseline: 1.1236x; 1.0562x over previous
//
#include <hip/hip_runtime.h>
#include <hip/hip_bf16.h>
#include <stdint.h>

#define DEV static __device__ __forceinline__

typedef __attribute__((ext_vector_type(8))) __bf16 bf16x8;
typedef __attribute__((ext_vector_type(4))) __bf16 bf16x4;
typedef __attribute__((ext_vector_type(4))) float f32x4;
typedef __attribute__((ext_vector_type(16))) float f32x16;

// B=2, T=2048, C=1024, NH=16, HS=64
#define BB 2
#define TT 2048
#define CC 1024
#define NHH 16
#define HSS 64
#define BT 4096
#define N3 3072

DEV unsigned short f2bf(float f) {
  union { float f; uint32_t u; } v; v.f = f;
  uint32_t r = v.u + 0x7FFFu + ((v.u >> 16) & 1u);
  return (unsigned short)(r >> 16);
}

typedef const __attribute__((address_space(1))) unsigned int* gas_t;
typedef __attribute__((address_space(3))) unsigned int* las_t;

DEV void glds16(const void* g, void* l) {
  __builtin_amdgcn_global_load_lds((gas_t)g, (las_t)l, 16, 0, 0);
}

DEV f32x4 mfma16(bf16x8 a, bf16x8 b, f32x4 c) {
  return __builtin_amdgcn_mfma_f32_16x16x32_bf16(a, b, c, 0, 0, 0);
}
DEV f32x16 mfma32(bf16x8 a, bf16x8 b, f32x16 c) {
  return __builtin_amdgcn_mfma_f32_32x32x16_bf16(a, b, c, 0, 0, 0);
}

DEV bf16x8 ld8(const unsigned short* p) { return *(const bf16x8*)p; }

DEV f32x16 z16() {
  f32x16 v;
#pragma unroll
  for (int i = 0; i < 16; i++) v[i] = 0.f;
  return v;
}

// ---------- fused prep: x conv (blocks 0..1023) + W_attn transp (1024..4095)
// + W_proj transp (4096..5119). 256 threads/block.
__global__ __launch_bounds__(256) void k_prep(const float* __restrict__ x,
                                              const float* __restrict__ Wa,
                                              const float* __restrict__ Wp,
                                              unsigned short* __restrict__ xb,
                                              unsigned short* __restrict__ wabt,
                                              unsigned short* __restrict__ wpbt) {
  const int bid = blockIdx.x;
  const int t = threadIdx.x;
  if (bid < 1024) {
    // conv: 1M float4, 1024 blocks x 256 thr x 4 iter
    int i = bid * 256 + t;
    const int n4 = BT * CC / 4;
#pragma unroll
    for (int r = 0; r < 4; r++, i += 262144) {
      if (i < n4) {
        float4 v = ((const float4*)x)[i];
        ushort4 o;
        o.x = f2bf(v.x); o.y = f2bf(v.y); o.z = f2bf(v.z); o.w = f2bf(v.w);
        ((ushort4*)xb)[i] = o;
      }
    }
    return;
  }
  // transpose+convert: in [K=1024][N] f32 -> out [N][1024] bf16
  __shared__ float tile[32][33];
  const float* in;
  unsigned short* out;
  int N, tid;
  if (bid < 4096) { in = Wa; out = wabt; N = N3; tid = bid - 1024; }   // 96x32 tiles
  else            { in = Wp; out = wpbt; N = CC; tid = bid - 4096; }   // 32x32 tiles
  const int ntx = N / 32;
  const int n0 = (tid % ntx) * 32, k0 = (tid / ntx) * 32;
  const int tx = t & 31, ty = t >> 5;  // (32,8)
  for (int r = ty; r < 32; r += 8)
    tile[r][tx] = in[(size_t)(k0 + r) * N + n0 + tx];
  __syncthreads();
  for (int r = ty; r < 32; r += 8)
    out[(size_t)(n0 + r) * CC + k0 + tx] = f2bf(tile[tx][r]);
}

// ---------- GEMM: A[M][K] bf16, Bt[N][K] bf16, bias f32[N] ----------
// 128x128 tile, BK=32, 8 waves (2M x 4N, 64x32 per wave), ring-3 LDS (48KB),
// depth-2 prefetch + counted vmcnt. XCD-region block decode: XCD grid Xm x Xn
// (Xm*Xn=8), per-XCD region Rm x Rn tiles (bounded L2 working set).
template <int OUT_BF16>
__global__ __launch_bounds__(512) void k_gemm(const unsigned short* __restrict__ A,
                                              const unsigned short* __restrict__ Bt,
                                              const float* __restrict__ bias,
                                              void* __restrict__ Cout,
                                              int N, int K, int Rm, int Rn, int Xn) {
  __shared__ __align__(16) unsigned short As[3][128 * 32];
  __shared__ __align__(16) unsigned short Bs[3][128 * 32];
  const int t = threadIdx.x;
  const int wave = t >> 6, l = t & 63, lr = l & 15, lg = l >> 4;
  const int xcd = (int)blockIdx.x & 7, q = (int)blockIdx.x >> 3;
  const int m0 = ((xcd / Xn) * Rm + (q % Rm)) * 128;
  const int n0 = ((xcd % Xn) * Rn + (q / Rm)) * 128;
  const int wm = wave >> 2, wn = wave & 3;

  f32x4 acc[4][2] = {};

  // staging map: thread t -> row t>>2 (0..127), chunk (t&3)*16B; one issue/array
  const unsigned short* gA = A + (size_t)(m0 + (t >> 2)) * K + (t & 3) * 8;
  const unsigned short* gB = Bt + (size_t)(n0 + (t >> 2)) * K + (t & 3) * 8;

#define GSTAGE(buf_, k_)                                                  \
  do {                                                                    \
    glds16(gA + (k_), (char*)As[buf_] + t * 16);                          \
    glds16(gB + (k_), (char*)Bs[buf_] + t * 16);                          \
  } while (0)

  const int nst = K >> 5;
  GSTAGE(0, 0);
  GSTAGE(1, 32);

  for (int st = 0; st < nst; ++st) {
    __builtin_amdgcn_s_barrier();          // A: guards slot (st+2)%3 overwrite
    __builtin_amdgcn_sched_barrier(0);
    if (st + 2 < nst) GSTAGE((st + 2) % 3, (st + 2) * 32);
    __builtin_amdgcn_sched_barrier(0);
    if (st + 2 < nst)      asm volatile("s_waitcnt vmcnt(4)" ::: "memory");
    else if (st + 1 < nst) asm volatile("s_waitcnt vmcnt(2)" ::: "memory");
    else                   asm volatile("s_waitcnt vmcnt(0)" ::: "memory");
    __builtin_amdgcn_s_barrier();          // B: all waves' stage(st) visible
    __builtin_amdgcn_sched_barrier(0);

    const unsigned short* Ab = As[st % 3];
    const unsigned short* Bb = Bs[st % 3];
    bf16x8 av[4], bv[2];
#pragma unroll
    for (int i = 0; i < 4; i++)
      av[i] = ld8(Ab + (wm * 64 + i * 16 + lr) * 32 + lg * 8);
#pragma unroll
    for (int j = 0; j < 2; j++)
      bv[j] = ld8(Bb + (wn * 32 + j * 16 + lr) * 32 + lg * 8);
    __builtin_amdgcn_s_setprio(1);
#pragma unroll
    for (int i = 0; i < 4; i++)
#pragma unroll
      for (int j = 0; j < 2; j++)
        acc[i][j] = mfma16(av[i], bv[j], acc[i][j]);
    __builtin_amdgcn_s_setprio(0);
  }
#undef GSTAGE

#pragma unroll
  for (int j2 = 0; j2 < 2; j2++) {
    int col = n0 + wn * 32 + j2 * 16 + lr;
    float bv_ = bias[col];
#pragma unroll
    for (int i = 0; i < 4; i++) {
      int row = m0 + wm * 64 + i * 16 + lg * 4;
#pragma unroll
      for (int r = 0; r < 4; r++) {
        float v = acc[i][j2][r] + bv_;
        if (OUT_BF16)
          ((unsigned short*)Cout)[(size_t)(row + r) * N + col] = f2bf(v);
        else
          ((float*)Cout)[(size_t)(row + r) * N + col] = v;
      }
    }
  }
}

// ---------- per-head V transpose: qkv[b][t][2048+h*64+d] -> vt[bh][d][t] ----------
__global__ void k_vt(const unsigned short* __restrict__ qkv, unsigned short* __restrict__ vt) {
  __shared__ unsigned short tile[64][65];
  int bh = blockIdx.y, t0 = blockIdx.x * 64;
  int b = bh >> 4, h = bh & 15;
  int tx = threadIdx.x, ty = threadIdx.y;  // (64,4)
  const unsigned short* src = qkv + (size_t)(b * TT + t0) * N3 + 2 * CC + h * HSS;
  for (int r = ty; r < 64; r += 4)
    tile[r][tx] = src[(size_t)r * N3 + tx];
  __syncthreads();
  unsigned short* dst = vt + (size_t)bh * HSS * TT + t0;
  for (int r = ty; r < 64; r += 4)
    dst[(size_t)r * TT + tx] = tile[tx][r];
}

// ---------- flash attention: 8 waves, kv-parity split, paired q-tiles ----------
// (round-9 version, proven 42us) 256 blocks x 8 waves. Block = (bh, p):
// segment A = q-tile 15-p, then B = p. Wave = (qsub 0..3, par 0..1). Ring-3
// K/V LDS, depth-1 prefetch + counted vmcnt(4). Parity merge through Ps.
__global__ __launch_bounds__(512) void k_attn(const unsigned short* __restrict__ qkv,
                                              const unsigned short* __restrict__ vt,
                                              unsigned short* __restrict__ y) {
  __shared__ __align__(16) unsigned short Ks[3][128 * 64];
  __shared__ __align__(16) unsigned short Vs[3][128 * 64];
  __shared__ __align__(16) unsigned short Ps[8][32 * 64];
  __shared__ float Msh[4][64];
  __shared__ float Lsh[4][64];
  const int t = threadIdx.x;
  const int w = t >> 6, l = t & 63, lq = l & 31, hl = l >> 5;
  const int qsub = w & 3, par = w >> 2;
  const int id = blockIdx.x;
  const int bh = (id & 7) + 8 * ((id >> 3) & 3);
  const int p = id >> 5;  // 0..7
  const int b = bh >> 4, head = bh & 15;
  const int jA = 15 - p, jB = p;
  const int mA = jA + 1;        // + (jB+1) = 17 macro-steps
  const int NT = 17;
  const float cexp = 0.18033688011112042f;  // (1/8)*log2(e)
  const float THR = 40.0f;

#define SWZ(r_) ((((r_) & 7) ^ (((r_) >> 3) & 3)) << 4)

  const int myswz = SWZ(lq);
  int offs[4];
#pragma unroll
  for (int s = 0; s < 4; s++) offs[s] = (32 * s + 16 * hl) ^ myswz;

  // staging: two glds16 issues per array; linear LDS off = i*8192 + w*1024 + l*16
  const int off0 = w * 1024 + l * 16;
  const int off1 = 8192 + w * 1024 + l * 16;
  const int rk0 = off0 >> 7, rk1 = off1 >> 7;          // K rows 0..127
  const int ck0 = (off0 & 127) ^ SWZ(rk0), ck1 = (off1 & 127) ^ SWZ(rk1);
  const int rv0 = rk0 & 63, rv1 = rk1 & 63;            // V rows 0..63, subtile = i
  const int cv0 = (off0 & 127) ^ SWZ(rv0), cv1 = (off1 & 127) ^ SWZ(rv1);
  const char* gK0 = (const char*)(qkv + (size_t)(b * TT + rk0) * N3 + CC + head * HSS) + ck0;
  const char* gK1 = (const char*)(qkv + (size_t)(b * TT + rk1) * N3 + CC + head * HSS) + ck1;
  const char* gV0 = (const char*)(vt + ((size_t)bh * HSS + rv0) * TT) + cv0;        // kv 0..63
  const char* gV1 = (const char*)(vt + ((size_t)bh * HSS + rv1) * TT + 64) + cv1;   // kv 64..127
  const int dK0 = w * 1024, dK1 = 8192 + w * 1024;

#define STAGE(slot_, kvt_)                                                \
  do {                                                                    \
    size_t kb = (size_t)(kvt_) * (128 * N3 * 2);                          \
    size_t vb = (size_t)(kvt_) * 256;                                     \
    glds16(gK0 + kb, (char*)Ks[slot_] + dK0);                             \
    glds16(gK1 + kb, (char*)Ks[slot_] + dK1);                             \
    glds16(gV0 + vb, (char*)Vs[slot_] + dK0);                             \
    glds16(gV1 + vb, (char*)Vs[slot_] + dK1);                             \
  } while (0)

#define WRITE_OUT()                                                       \
  do {                                                                    \
    float l_q = l_ln + __shfl_xor(l_ln, 32);                              \
    float inv = 1.0f / l_q;                                               \
    unsigned short* ybase = y + (size_t)(b * TT + q0w + lq) * CC + head * HSS; \
    _Pragma("unroll")                                                     \
    for (int g = 0; g < 4; g++) {                                         \
      ushort4 wv;                                                         \
      wv.x = f2bf(oa[4 * g + 0] * inv); wv.y = f2bf(oa[4 * g + 1] * inv); \
      wv.z = f2bf(oa[4 * g + 2] * inv); wv.w = f2bf(oa[4 * g + 3] * inv); \
      *(ushort4*)(ybase + 8 * g + 4 * hl) = wv;                           \
      ushort4 wv2;                                                        \
      wv2.x = f2bf(ob[4 * g + 0] * inv); wv2.y = f2bf(ob[4 * g + 1] * inv); \
      wv2.z = f2bf(ob[4 * g + 2] * inv); wv2.w = f2bf(ob[4 * g + 3] * inv); \
      *(ushort4*)(ybase + 32 + 8 * g + 4 * hl) = wv2;                     \
    }                                                                     \
  } while (0)

// cross-parity merge: par1 writes (oa,ob,m,l) through Ps; par0 combines + stores y
#define MERGE()                                                           \
  do {                                                                    \
    __builtin_amdgcn_s_barrier();                                         \
    if (par) {                                                            \
      float* poa = (float*)Ps[w];                                         \
      float* pob = (float*)Ps[w - 4];                                     \
      _Pragma("unroll")                                                   \
      for (int g = 0; g < 16; g++) { poa[g * 64 + l] = oa[g]; pob[g * 64 + l] = ob[g]; } \
      Msh[qsub][l] = m_s; Lsh[qsub][l] = l_ln;                            \
    }                                                                     \
    asm volatile("s_waitcnt lgkmcnt(0)" ::: "memory");                    \
    __builtin_amdgcn_s_barrier();                                         \
    __builtin_amdgcn_sched_barrier(0);                                    \
    if (!par) {                                                           \
      float m1 = Msh[qsub][l], l1 = Lsh[qsub][l];                         \
      float mstar = fmaxf(m_s, m1);                                       \
      float a0 = __builtin_amdgcn_exp2f((m_s - mstar) * cexp);            \
      float a1 = __builtin_amdgcn_exp2f((m1 - mstar) * cexp);             \
      const float* poa = (const float*)Ps[w + 4];                         \
      const float* pob = (const float*)Ps[w];                             \
      _Pragma("unroll")                                                   \
      for (int g = 0; g < 16; g++) {                                      \
        oa[g] = oa[g] * a0 + poa[g * 64 + l] * a1;                        \
        ob[g] = ob[g] * a0 + pob[g * 64 + l] * a1;                        \
      }                                                                   \
      l_ln = l_ln * a0 + l1 * a1;                                         \
      WRITE_OUT();                                                        \
    }                                                                     \
    __builtin_amdgcn_s_barrier();                                         \
  } while (0)

  // segment A state
  int q0w = jA * 128 + qsub * 32;
  const unsigned short* qp = qkv + (size_t)(b * TT + q0w + lq) * N3 + head * HSS + hl * 8;
  bf16x8 qf0 = ld8(qp), qf1 = ld8(qp + 16), qf2 = ld8(qp + 32), qf3 = ld8(qp + 48);
  float m_s = -INFINITY, l_ln = 0.f;
  f32x16 oa = z16(), ob = z16();
  char* prow = (char*)Ps[w] + lq * 128;

  STAGE(0, 0);
  int cur = 0;

  for (int seq = 0; seq < NT; ++seq) {
    if (seq == mA) {
      MERGE();  // finalize segment A; y written by par0
      q0w = jB * 128 + qsub * 32;
      const unsigned short* qp2 = qkv + (size_t)(b * TT + q0w + lq) * N3 + head * HSS + hl * 8;
      qf0 = ld8(qp2); qf1 = ld8(qp2 + 16); qf2 = ld8(qp2 + 32); qf3 = ld8(qp2 + 48);
      m_s = -INFINITY; l_ln = 0.f;
      oa = z16(); ob = z16();
    }

    const int kvt = (seq < mA) ? seq : (seq - mA);
    if (seq + 1 < NT) {
      int s2 = seq + 1;
      int kvt2 = (s2 < mA) ? s2 : (s2 - mA);
      int nxt = (cur == 2) ? 0 : cur + 1;
      STAGE(nxt, kvt2);
      __builtin_amdgcn_sched_barrier(0);
      asm volatile("s_waitcnt vmcnt(4)" ::: "memory");
    } else {
      asm volatile("s_waitcnt vmcnt(0)" ::: "memory");
    }
    __builtin_amdgcn_s_barrier();
    __builtin_amdgcn_sched_barrier(0);

    const int mybuf = cur;
    cur = (cur == 2) ? 0 : cur + 1;

    const int kv0w = kvt * 128 + 64 * par;
    if (kv0w > q0w + 31) continue;  // fully-masked for this wave (barriers done)

    const unsigned short* Kb = Ks[mybuf];
    const unsigned short* Vb = Vs[mybuf];

    // QK^T swapped: sa/sb hold S^T[kv][q=lq], kv=kv0w+(g&3)+8*(g>>2)+4*hl (+32 sb)
    const char* krA = (const char*)Kb + (64 * par + lq) * 128;
    const char* krB = krA + 32 * 128;
    f32x16 sa = z16(), sb = z16();
    __builtin_amdgcn_s_setprio(1);
    {
      bf16x8 ka, kb8;
      ka = ld8((const unsigned short*)(krA + offs[0]));
      kb8 = ld8((const unsigned short*)(krB + offs[0]));
      sa = mfma32(ka, qf0, sa); sb = mfma32(kb8, qf0, sb);
      ka = ld8((const unsigned short*)(krA + offs[1]));
      kb8 = ld8((const unsigned short*)(krB + offs[1]));
      sa = mfma32(ka, qf1, sa); sb = mfma32(kb8, qf1, sb);
      ka = ld8((const unsigned short*)(krA + offs[2]));
      kb8 = ld8((const unsigned short*)(krB + offs[2]));
      sa = mfma32(ka, qf2, sa); sb = mfma32(kb8, qf2, sb);
      ka = ld8((const unsigned short*)(krA + offs[3]));
      kb8 = ld8((const unsigned short*)(krB + offs[3]));
      sa = mfma32(ka, qf3, sa); sb = mfma32(kb8, qf3, sb);
    }
    __builtin_amdgcn_s_setprio(0);

    // causal mask near the diagonal
    if (kv0w + 63 > q0w) {
      const int q = q0w + lq;
#pragma unroll
      for (int g = 0; g < 16; g++) {
        int kvl = kv0w + (g & 3) + 8 * (g >> 2) + 4 * hl;
        if (kvl > q) sa[g] = -INFINITY;
        if (kvl + 32 > q) sb[g] = -INFINITY;
      }
    }

    // per-lane max + cross-half combine
    float tmax = -INFINITY;
#pragma unroll
    for (int g = 0; g < 16; g++) tmax = fmaxf(tmax, fmaxf(sa[g], sb[g]));
    tmax = fmaxf(tmax, __shfl_xor(tmax, 32));

    if (!__all(tmax <= m_s + THR)) {
      float m_new = fmaxf(m_s, tmax);
      float alpha = __builtin_amdgcn_exp2f((m_s - m_new) * cexp);
      l_ln *= alpha;
#pragma unroll
      for (int g = 0; g < 16; g++) { oa[g] *= alpha; ob[g] *= alpha; }
      m_s = m_new;
    }

    // exp in place; accumulate per-lane l
    const float mc = m_s * cexp;
    float tsum = 0.f;
#pragma unroll
    for (int g = 0; g < 16; g++) {
      sa[g] = __builtin_amdgcn_exp2f(__builtin_fmaf(sa[g], cexp, -mc));
      sb[g] = __builtin_amdgcn_exp2f(__builtin_fmaf(sb[g], cexp, -mc));
      tsum += sa[g] + sb[g];
    }
    l_ln += tsum;

    // P -> LDS bounce (wave-private)
#pragma unroll
    for (int u2 = 0; u2 < 4; u2++) {
      bf16x4 w0, w1;
#pragma unroll
      for (int r = 0; r < 4; r++) { w0[r] = (__bf16)sa[4 * u2 + r]; w1[r] = (__bf16)sb[4 * u2 + r]; }
      *(bf16x4*)(prow + ((16 * u2 + 8 * hl) ^ myswz)) = w0;
      *(bf16x4*)(prow + ((64 + 16 * u2 + 8 * hl) ^ myswz)) = w1;
    }
    asm volatile("s_waitcnt lgkmcnt(0)" ::: "memory");
    __builtin_amdgcn_sched_barrier(0);
    bf16x8 pf0 = ld8((const unsigned short*)(prow + offs[0]));
    bf16x8 pf1 = ld8((const unsigned short*)(prow + offs[1]));
    bf16x8 pf2 = ld8((const unsigned short*)(prow + offs[2]));
    bf16x8 pf3 = ld8((const unsigned short*)(prow + offs[3]));

    // PV on this wave's V subtile (kv parity half)
    const char* vrA = (const char*)Vb + par * 8192 + lq * 128;
    const char* vrB = vrA + 32 * 128;
    __builtin_amdgcn_s_setprio(1);
    {
      bf16x8 va, vb8;
      va = ld8((const unsigned short*)(vrA + offs[0]));
      vb8 = ld8((const unsigned short*)(vrB + offs[0]));
      oa = mfma32(va, pf0, oa); ob = mfma32(vb8, pf0, ob);
      va = ld8((const unsigned short*)(vrA + offs[1]));
      vb8 = ld8((const unsigned short*)(vrB + offs[1]));
      oa = mfma32(va, pf1, oa); ob = mfma32(vb8, pf1, ob);
      va = ld8((const unsigned short*)(vrA + offs[2]));
      vb8 = ld8((const unsigned short*)(vrB + offs[2]));
      oa = mfma32(va, pf2, oa); ob = mfma32(vb8, pf2, ob);
      va = ld8((const unsigned short*)(vrA + offs[3]));
      vb8 = ld8((const unsigned short*)(vrB + offs[3]));
      oa = mfma32(va, pf3, oa); ob = mfma32(vb8, pf3, ob);
    }
    __builtin_amdgcn_s_setprio(0);
  }

  MERGE();  // finalize segment B
#undef STAGE
#undef WRITE_OUT
#undef MERGE
#undef SWZ
}

extern "C" void kernel_launch(void* const* d_in, const int* in_sizes, int n_in,
                              void* d_out, int out_size, void* d_ws, size_t ws_size,
                              hipStream_t stream) {
  const float* x = (const float*)d_in[0];
  const float* W_attn = (const float*)d_in[1];
  const float* b_attn = (const float*)d_in[2];
  const float* W_proj = (const float*)d_in[3];
  const float* b_proj = (const float*)d_in[4];

  char* ws = (char*)d_ws;
  unsigned short* xb   = (unsigned short*)(ws);                       // 8 MB
  unsigned short* wabt = (unsigned short*)(ws + 8388608);             // 6 MB  [3072][1024]
  unsigned short* wpbt = (unsigned short*)(ws + 14680064);            // 2 MB  [1024][1024]
  unsigned short* qkvb = (unsigned short*)(ws + 16777216);            // 24 MB [4096][3072]
  unsigned short* vt   = (unsigned short*)(ws + 41943040);            // 8 MB  [32][64][2048]
  unsigned short* yb   = (unsigned short*)(ws + 50331648);            // 8 MB  [4096][1024]

  k_prep<<<dim3(5120), 256, 0, stream>>>(x, W_attn, W_proj, xb, wabt, wpbt);
  // QKV: M=4096, N=3072 -> 32x24 tiles = 768 blocks; XCD grid 4x2, region 8Mx12N
  k_gemm<1><<<dim3(768), 512, 0, stream>>>(xb, wabt, b_attn, qkvb, N3, CC, 8, 12, 2);
  k_vt<<<dim3(TT / 64, BB * NHH), dim3(64, 4), 0, stream>>>(qkvb, vt);
  k_attn<<<dim3(256), 512, 0, stream>>>(qkvb, vt, yb);
  // proj: M=4096, N=1024 -> 32x8 tiles = 256 blocks; XCD grid 8x1, region 4Mx8N
  k_gemm<0><<<dim3(256), 512, 0, stream>>>(yb, wpbt, b_proj, d_out, CC, CC, 4, 8, 1);
}

// Round 15
// 106.317 us; speedup vs baseline: 1.1595x; 1.0320x over previous
//
#include <hip/hip_runtime.h>
#include <hip/hip_bf16.h>
#include <stdint.h>

#define DEV static __device__ __forceinline__

typedef __attribute__((ext_vector_type(8))) __bf16 bf16x8;
typedef __attribute__((ext_vector_type(4))) __bf16 bf16x4;
typedef __attribute__((ext_vector_type(4))) float f32x4;
typedef __attribute__((ext_vector_type(16))) float f32x16;

// B=2, T=2048, C=1024, NH=16, HS=64
#define BB 2
#define TT 2048
#define CC 1024
#define NHH 16
#define HSS 64
#define BT 4096
#define N3 3072

DEV unsigned short f2bf(float f) {
  union { float f; uint32_t u; } v; v.f = f;
  uint32_t r = v.u + 0x7FFFu + ((v.u >> 16) & 1u);
  return (unsigned short)(r >> 16);
}

typedef const __attribute__((address_space(1))) unsigned int* gas_t;
typedef __attribute__((address_space(3))) unsigned int* las_t;

DEV void glds16(const void* g, void* l) {
  __builtin_amdgcn_global_load_lds((gas_t)g, (las_t)l, 16, 0, 0);
}

DEV f32x4 mfma16(bf16x8 a, bf16x8 b, f32x4 c) {
  return __builtin_amdgcn_mfma_f32_16x16x32_bf16(a, b, c, 0, 0, 0);
}
DEV f32x16 mfma32(bf16x8 a, bf16x8 b, f32x16 c) {
  return __builtin_amdgcn_mfma_f32_32x32x16_bf16(a, b, c, 0, 0, 0);
}

DEV bf16x8 ld8(const unsigned short* p) { return *(const bf16x8*)p; }

DEV f32x16 z16() {
  f32x16 v;
#pragma unroll
  for (int i = 0; i < 16; i++) v[i] = 0.f;
  return v;
}

// ---------- fused prep: x conv (blocks 0..1023) + W_attn transp (1024..4095)
// + W_proj transp (4096..5119). 256 threads/block.
__global__ __launch_bounds__(256) void k_prep(const float* __restrict__ x,
                                              const float* __restrict__ Wa,
                                              const float* __restrict__ Wp,
                                              unsigned short* __restrict__ xb,
                                              unsigned short* __restrict__ wabt,
                                              unsigned short* __restrict__ wpbt) {
  const int bid = blockIdx.x;
  const int t = threadIdx.x;
  if (bid < 1024) {
    int i = bid * 256 + t;
    const int n4 = BT * CC / 4;
#pragma unroll
    for (int r = 0; r < 4; r++, i += 262144) {
      if (i < n4) {
        float4 v = ((const float4*)x)[i];
        ushort4 o;
        o.x = f2bf(v.x); o.y = f2bf(v.y); o.z = f2bf(v.z); o.w = f2bf(v.w);
        ((ushort4*)xb)[i] = o;
      }
    }
    return;
  }
  __shared__ float tile[32][33];
  const float* in;
  unsigned short* out;
  int N, tid;
  if (bid < 4096) { in = Wa; out = wabt; N = N3; tid = bid - 1024; }
  else            { in = Wp; out = wpbt; N = CC; tid = bid - 4096; }
  const int ntx = N / 32;
  const int n0 = (tid % ntx) * 32, k0 = (tid / ntx) * 32;
  const int tx = t & 31, ty = t >> 5;
  for (int r = ty; r < 32; r += 8)
    tile[r][tx] = in[(size_t)(k0 + r) * N + n0 + tx];
  __syncthreads();
  for (int r = ty; r < 32; r += 8)
    out[(size_t)(n0 + r) * CC + k0 + tx] = f2bf(tile[tx][r]);
}

// ---------- GEMM: A[M][K] bf16, Bt[N][K] bf16, bias f32[N] ----------
// 128x128 tile, BK=32, 8 waves (2M x 4N, 64x32 per wave), ring-3 LDS (48KB),
// depth-2 prefetch + counted vmcnt. XCD-region decode. When vtOut != nullptr
// and the tile is in the V third (n0 >= 2048), the epilogue writes the
// per-head transposed V layout vt[bh][d][t] directly (replaces k_vt).
template <int OUT_BF16>
__global__ __launch_bounds__(512) void k_gemm(const unsigned short* __restrict__ A,
                                              const unsigned short* __restrict__ Bt,
                                              const float* __restrict__ bias,
                                              void* __restrict__ Cout,
                                              unsigned short* __restrict__ vtOut,
                                              int N, int K, int Rm, int Rn, int Xn) {
  __shared__ __align__(16) unsigned short As[3][128 * 32];
  __shared__ __align__(16) unsigned short Bs[3][128 * 32];
  const int t = threadIdx.x;
  const int wave = t >> 6, l = t & 63, lr = l & 15, lg = l >> 4;
  const int xcd = (int)blockIdx.x & 7, q = (int)blockIdx.x >> 3;
  const int m0 = ((xcd / Xn) * Rm + (q % Rm)) * 128;
  const int n0 = ((xcd % Xn) * Rn + (q / Rm)) * 128;
  const int wm = wave >> 2, wn = wave & 3;

  f32x4 acc[4][2] = {};

  const unsigned short* gA = A + (size_t)(m0 + (t >> 2)) * K + (t & 3) * 8;
  const unsigned short* gB = Bt + (size_t)(n0 + (t >> 2)) * K + (t & 3) * 8;

#define GSTAGE(buf_, k_)                                                  \
  do {                                                                    \
    glds16(gA + (k_), (char*)As[buf_] + t * 16);                          \
    glds16(gB + (k_), (char*)Bs[buf_] + t * 16);                          \
  } while (0)

  const int nst = K >> 5;
  GSTAGE(0, 0);
  GSTAGE(1, 32);

  for (int st = 0; st < nst; ++st) {
    __builtin_amdgcn_s_barrier();          // A: guards slot (st+2)%3 overwrite
    __builtin_amdgcn_sched_barrier(0);
    if (st + 2 < nst) GSTAGE((st + 2) % 3, (st + 2) * 32);
    __builtin_amdgcn_sched_barrier(0);
    if (st + 2 < nst)      asm volatile("s_waitcnt vmcnt(4)" ::: "memory");
    else if (st + 1 < nst) asm volatile("s_waitcnt vmcnt(2)" ::: "memory");
    else                   asm volatile("s_waitcnt vmcnt(0)" ::: "memory");
    __builtin_amdgcn_s_barrier();          // B: all waves' stage(st) visible
    __builtin_amdgcn_sched_barrier(0);

    const unsigned short* Ab = As[st % 3];
    const unsigned short* Bb = Bs[st % 3];
    bf16x8 av[4], bv[2];
#pragma unroll
    for (int i = 0; i < 4; i++)
      av[i] = ld8(Ab + (wm * 64 + i * 16 + lr) * 32 + lg * 8);
#pragma unroll
    for (int j = 0; j < 2; j++)
      bv[j] = ld8(Bb + (wn * 32 + j * 16 + lr) * 32 + lg * 8);
    __builtin_amdgcn_s_setprio(1);
#pragma unroll
    for (int i = 0; i < 4; i++)
#pragma unroll
      for (int j = 0; j < 2; j++)
        acc[i][j] = mfma16(av[i], bv[j], acc[i][j]);
    __builtin_amdgcn_s_setprio(0);
  }
#undef GSTAGE

  if (OUT_BF16 && vtOut != nullptr && n0 >= 2 * CC) {
    // V third: write vt[bh][d][t] directly (b=row>>11, t=row&2047)
#pragma unroll
    for (int j2 = 0; j2 < 2; j2++) {
      int cv = n0 - 2 * CC + wn * 32 + j2 * 16 + lr;  // h*64 + d
      int h = cv >> 6, d = cv & 63;
      float bv_ = bias[2 * CC + cv];
#pragma unroll
      for (int i = 0; i < 4; i++) {
        int row = m0 + wm * 64 + i * 16 + lg * 4;
        int bb = row >> 11, t2 = row & 2047;
        ushort4 wv;
        wv.x = f2bf(acc[i][j2][0] + bv_);
        wv.y = f2bf(acc[i][j2][1] + bv_);
        wv.z = f2bf(acc[i][j2][2] + bv_);
        wv.w = f2bf(acc[i][j2][3] + bv_);
        *(ushort4*)(vtOut + (((size_t)(bb * NHH + h) * HSS + d) << 11) + t2) = wv;
      }
    }
    return;
  }

#pragma unroll
  for (int j2 = 0; j2 < 2; j2++) {
    int col = n0 + wn * 32 + j2 * 16 + lr;
    float bv_ = bias[col];
#pragma unroll
    for (int i = 0; i < 4; i++) {
      int row = m0 + wm * 64 + i * 16 + lg * 4;
#pragma unroll
      for (int r = 0; r < 4; r++) {
        float v = acc[i][j2][r] + bv_;
        if (OUT_BF16)
          ((unsigned short*)Cout)[(size_t)(row + r) * N + col] = f2bf(v);
        else
          ((float*)Cout)[(size_t)(row + r) * N + col] = v;
      }
    }
  }
}

// ---------- flash attention: 8 waves, kv-parity split, paired q-tiles ----------
// (round-9 version, proven 42us) 256 blocks x 8 waves. Block = (bh, p):
// segment A = q-tile 15-p, then B = p. Wave = (qsub 0..3, par 0..1). Ring-3
// K/V LDS, depth-1 prefetch + counted vmcnt(4). Parity merge through Ps.
__global__ __launch_bounds__(512) void k_attn(const unsigned short* __restrict__ qkv,
                                              const unsigned short* __restrict__ vt,
                                              unsigned short* __restrict__ y) {
  __shared__ __align__(16) unsigned short Ks[3][128 * 64];
  __shared__ __align__(16) unsigned short Vs[3][128 * 64];
  __shared__ __align__(16) unsigned short Ps[8][32 * 64];
  __shared__ float Msh[4][64];
  __shared__ float Lsh[4][64];
  const int t = threadIdx.x;
  const int w = t >> 6, l = t & 63, lq = l & 31, hl = l >> 5;
  const int qsub = w & 3, par = w >> 2;
  const int id = blockIdx.x;
  const int bh = (id & 7) + 8 * ((id >> 3) & 3);
  const int p = id >> 5;  // 0..7
  const int b = bh >> 4, head = bh & 15;
  const int jA = 15 - p, jB = p;
  const int mA = jA + 1;        // + (jB+1) = 17 macro-steps
  const int NT = 17;
  const float cexp = 0.18033688011112042f;  // (1/8)*log2(e)
  const float THR = 40.0f;

#define SWZ(r_) ((((r_) & 7) ^ (((r_) >> 3) & 3)) << 4)

  const int myswz = SWZ(lq);
  int offs[4];
#pragma unroll
  for (int s = 0; s < 4; s++) offs[s] = (32 * s + 16 * hl) ^ myswz;

  // staging: two glds16 issues per array; linear LDS off = i*8192 + w*1024 + l*16
  const int off0 = w * 1024 + l * 16;
  const int off1 = 8192 + w * 1024 + l * 16;
  const int rk0 = off0 >> 7, rk1 = off1 >> 7;          // K rows 0..127
  const int ck0 = (off0 & 127) ^ SWZ(rk0), ck1 = (off1 & 127) ^ SWZ(rk1);
  const int rv0 = rk0 & 63, rv1 = rk1 & 63;            // V rows 0..63, subtile = i
  const int cv0 = (off0 & 127) ^ SWZ(rv0), cv1 = (off1 & 127) ^ SWZ(rv1);
  const char* gK0 = (const char*)(qkv + (size_t)(b * TT + rk0) * N3 + CC + head * HSS) + ck0;
  const char* gK1 = (const char*)(qkv + (size_t)(b * TT + rk1) * N3 + CC + head * HSS) + ck1;
  const char* gV0 = (const char*)(vt + ((size_t)bh * HSS + rv0) * TT) + cv0;        // kv 0..63
  const char* gV1 = (const char*)(vt + ((size_t)bh * HSS + rv1) * TT + 64) + cv1;   // kv 64..127
  const int dK0 = w * 1024, dK1 = 8192 + w * 1024;

#define STAGE(slot_, kvt_)                                                \
  do {                                                                    \
    size_t kb = (size_t)(kvt_) * (128 * N3 * 2);                          \
    size_t vb = (size_t)(kvt_) * 256;                                     \
    glds16(gK0 + kb, (char*)Ks[slot_] + dK0);                             \
    glds16(gK1 + kb, (char*)Ks[slot_] + dK1);                             \
    glds16(gV0 + vb, (char*)Vs[slot_] + dK0);                             \
    glds16(gV1 + vb, (char*)Vs[slot_] + dK1);                             \
  } while (0)

#define WRITE_OUT()                                                       \
  do {                                                                    \
    float l_q = l_ln + __shfl_xor(l_ln, 32);                              \
    float inv = 1.0f / l_q;                                               \
    unsigned short* ybase = y + (size_t)(b * TT + q0w + lq) * CC + head * HSS; \
    _Pragma("unroll")                                                     \
    for (int g = 0; g < 4; g++) {                                         \
      ushort4 wv;                                                         \
      wv.x = f2bf(oa[4 * g + 0] * inv); wv.y = f2bf(oa[4 * g + 1] * inv); \
      wv.z = f2bf(oa[4 * g + 2] * inv); wv.w = f2bf(oa[4 * g + 3] * inv); \
      *(ushort4*)(ybase + 8 * g + 4 * hl) = wv;                           \
      ushort4 wv2;                                                        \
      wv2.x = f2bf(ob[4 * g + 0] * inv); wv2.y = f2bf(ob[4 * g + 1] * inv); \
      wv2.z = f2bf(ob[4 * g + 2] * inv); wv2.w = f2bf(ob[4 * g + 3] * inv); \
      *(ushort4*)(ybase + 32 + 8 * g + 4 * hl) = wv2;                     \
    }                                                                     \
  } while (0)

// cross-parity merge: par1 writes (oa,ob,m,l) through Ps; par0 combines + stores y
#define MERGE()                                                           \
  do {                                                                    \
    __builtin_amdgcn_s_barrier();                                         \
    if (par) {                                                            \
      float* poa = (float*)Ps[w];                                         \
      float* pob = (float*)Ps[w - 4];                                     \
      _Pragma("unroll")                                                   \
      for (int g = 0; g < 16; g++) { poa[g * 64 + l] = oa[g]; pob[g * 64 + l] = ob[g]; } \
      Msh[qsub][l] = m_s; Lsh[qsub][l] = l_ln;                            \
    }                                                                     \
    asm volatile("s_waitcnt lgkmcnt(0)" ::: "memory");                    \
    __builtin_amdgcn_s_barrier();                                         \
    __builtin_amdgcn_sched_barrier(0);                                    \
    if (!par) {                                                           \
      float m1 = Msh[qsub][l], l1 = Lsh[qsub][l];                         \
      float mstar = fmaxf(m_s, m1);                                       \
      float a0 = __builtin_amdgcn_exp2f((m_s - mstar) * cexp);            \
      float a1 = __builtin_amdgcn_exp2f((m1 - mstar) * cexp);             \
      const float* poa = (const float*)Ps[w + 4];                         \
      const float* pob = (const float*)Ps[w];                             \
      _Pragma("unroll")                                                   \
      for (int g = 0; g < 16; g++) {                                      \
        oa[g] = oa[g] * a0 + poa[g * 64 + l] * a1;                        \
        ob[g] = ob[g] * a0 + pob[g * 64 + l] * a1;                        \
      }                                                                   \
      l_ln = l_ln * a0 + l1 * a1;                                         \
      WRITE_OUT();                                                        \
    }                                                                     \
    __builtin_amdgcn_s_barrier();                                         \
  } while (0)

  // segment A state
  int q0w = jA * 128 + qsub * 32;
  const unsigned short* qp = qkv + (size_t)(b * TT + q0w + lq) * N3 + head * HSS + hl * 8;
  bf16x8 qf0 = ld8(qp), qf1 = ld8(qp + 16), qf2 = ld8(qp + 32), qf3 = ld8(qp + 48);
  float m_s = -INFINITY, l_ln = 0.f;
  f32x16 oa = z16(), ob = z16();
  char* prow = (char*)Ps[w] + lq * 128;

  STAGE(0, 0);
  int cur = 0;

  for (int seq = 0; seq < NT; ++seq) {
    if (seq == mA) {
      MERGE();  // finalize segment A; y written by par0
      q0w = jB * 128 + qsub * 32;
      const unsigned short* qp2 = qkv + (size_t)(b * TT + q0w + lq) * N3 + head * HSS + hl * 8;
      qf0 = ld8(qp2); qf1 = ld8(qp2 + 16); qf2 = ld8(qp2 + 32); qf3 = ld8(qp2 + 48);
      m_s = -INFINITY; l_ln = 0.f;
      oa = z16(); ob = z16();
    }

    const int kvt = (seq < mA) ? seq : (seq - mA);
    if (seq + 1 < NT) {
      int s2 = seq + 1;
      int kvt2 = (s2 < mA) ? s2 : (s2 - mA);
      int nxt = (cur == 2) ? 0 : cur + 1;
      STAGE(nxt, kvt2);
      __builtin_amdgcn_sched_barrier(0);
      asm volatile("s_waitcnt vmcnt(4)" ::: "memory");
    } else {
      asm volatile("s_waitcnt vmcnt(0)" ::: "memory");
    }
    __builtin_amdgcn_s_barrier();
    __builtin_amdgcn_sched_barrier(0);

    const int mybuf = cur;
    cur = (cur == 2) ? 0 : cur + 1;

    const int kv0w = kvt * 128 + 64 * par;
    if (kv0w > q0w + 31) continue;  // fully-masked for this wave (barriers done)

    const unsigned short* Kb = Ks[mybuf];
    const unsigned short* Vb = Vs[mybuf];

    // QK^T swapped: sa/sb hold S^T[kv][q=lq], kv=kv0w+(g&3)+8*(g>>2)+4*hl (+32 sb)
    const char* krA = (const char*)Kb + (64 * par + lq) * 128;
    const char* krB = krA + 32 * 128;
    f32x16 sa = z16(), sb = z16();
    __builtin_amdgcn_s_setprio(1);
    {
      bf16x8 ka, kb8;
      ka = ld8((const unsigned short*)(krA + offs[0]));
      kb8 = ld8((const unsigned short*)(krB + offs[0]));
      sa = mfma32(ka, qf0, sa); sb = mfma32(kb8, qf0, sb);
      ka = ld8((const unsigned short*)(krA + offs[1]));
      kb8 = ld8((const unsigned short*)(krB + offs[1]));
      sa = mfma32(ka, qf1, sa); sb = mfma32(kb8, qf1, sb);
      ka = ld8((const unsigned short*)(krA + offs[2]));
      kb8 = ld8((const unsigned short*)(krB + offs[2]));
      sa = mfma32(ka, qf2, sa); sb = mfma32(kb8, qf2, sb);
      ka = ld8((const unsigned short*)(krA + offs[3]));
      kb8 = ld8((const unsigned short*)(krB + offs[3]));
      sa = mfma32(ka, qf3, sa); sb = mfma32(kb8, qf3, sb);
    }
    __builtin_amdgcn_s_setprio(0);

    // causal mask near the diagonal
    if (kv0w + 63 > q0w) {
      const int q = q0w + lq;
#pragma unroll
      for (int g = 0; g < 16; g++) {
        int kvl = kv0w + (g & 3) + 8 * (g >> 2) + 4 * hl;
        if (kvl > q) sa[g] = -INFINITY;
        if (kvl + 32 > q) sb[g] = -INFINITY;
      }
    }

    // per-lane max + cross-half combine
    float tmax = -INFINITY;
#pragma unroll
    for (int g = 0; g < 16; g++) tmax = fmaxf(tmax, fmaxf(sa[g], sb[g]));
    tmax = fmaxf(tmax, __shfl_xor(tmax, 32));

    if (!__all(tmax <= m_s + THR)) {
      float m_new = fmaxf(m_s, tmax);
      float alpha = __builtin_amdgcn_exp2f((m_s - m_new) * cexp);
      l_ln *= alpha;
#pragma unroll
      for (int g = 0; g < 16; g++) { oa[g] *= alpha; ob[g] *= alpha; }
      m_s = m_new;
    }

    // exp in place; accumulate per-lane l
    const float mc = m_s * cexp;
    float tsum = 0.f;
#pragma unroll
    for (int g = 0; g < 16; g++) {
      sa[g] = __builtin_amdgcn_exp2f(__builtin_fmaf(sa[g], cexp, -mc));
      sb[g] = __builtin_amdgcn_exp2f(__builtin_fmaf(sb[g], cexp, -mc));
      tsum += sa[g] + sb[g];
    }
    l_ln += tsum;

    // P -> LDS bounce (wave-private)
#pragma unroll
    for (int u2 = 0; u2 < 4; u2++) {
      bf16x4 w0, w1;
#pragma unroll
      for (int r = 0; r < 4; r++) { w0[r] = (__bf16)sa[4 * u2 + r]; w1[r] = (__bf16)sb[4 * u2 + r]; }
      *(bf16x4*)(prow + ((16 * u2 + 8 * hl) ^ myswz)) = w0;
      *(bf16x4*)(prow + ((64 + 16 * u2 + 8 * hl) ^ myswz)) = w1;
    }
    asm volatile("s_waitcnt lgkmcnt(0)" ::: "memory");
    __builtin_amdgcn_sched_barrier(0);
    bf16x8 pf0 = ld8((const unsigned short*)(prow + offs[0]));
    bf16x8 pf1 = ld8((const unsigned short*)(prow + offs[1]));
    bf16x8 pf2 = ld8((const unsigned short*)(prow + offs[2]));
    bf16x8 pf3 = ld8((const unsigned short*)(prow + offs[3]));

    // PV on this wave's V subtile (kv parity half)
    const char* vrA = (const char*)Vb + par * 8192 + lq * 128;
    const char* vrB = vrA + 32 * 128;
    __builtin_amdgcn_s_setprio(1);
    {
      bf16x8 va, vb8;
      va = ld8((const unsigned short*)(vrA + offs[0]));
      vb8 = ld8((const unsigned short*)(vrB + offs[0]));
      oa = mfma32(va, pf0, oa); ob = mfma32(vb8, pf0, ob);
      va = ld8((const unsigned short*)(vrA + offs[1]));
      vb8 = ld8((const unsigned short*)(vrB + offs[1]));
      oa = mfma32(va, pf1, oa); ob = mfma32(vb8, pf1, ob);
      va = ld8((const unsigned short*)(vrA + offs[2]));
      vb8 = ld8((const unsigned short*)(vrB + offs[2]));
      oa = mfma32(va, pf2, oa); ob = mfma32(vb8, pf2, ob);
      va = ld8((const unsigned short*)(vrA + offs[3]));
      vb8 = ld8((const unsigned short*)(vrB + offs[3]));
      oa = mfma32(va, pf3, oa); ob = mfma32(vb8, pf3, ob);
    }
    __builtin_amdgcn_s_setprio(0);
  }

  MERGE();  // finalize segment B
#undef STAGE
#undef WRITE_OUT
#undef MERGE
#undef SWZ
}

extern "C" void kernel_launch(void* const* d_in, const int* in_sizes, int n_in,
                              void* d_out, int out_size, void* d_ws, size_t ws_size,
                              hipStream_t stream) {
  const float* x = (const float*)d_in[0];
  const float* W_attn = (const float*)d_in[1];
  const float* b_attn = (const float*)d_in[2];
  const float* W_proj = (const float*)d_in[3];
  const float* b_proj = (const float*)d_in[4];

  char* ws = (char*)d_ws;
  unsigned short* xb   = (unsigned short*)(ws);                       // 8 MB
  unsigned short* wabt = (unsigned short*)(ws + 8388608);             // 6 MB  [3072][1024]
  unsigned short* wpbt = (unsigned short*)(ws + 14680064);            // 2 MB  [1024][1024]
  unsigned short* qkvb = (unsigned short*)(ws + 16777216);            // 24 MB [4096][3072]
  unsigned short* vt   = (unsigned short*)(ws + 41943040);            // 8 MB  [32][64][2048]
  unsigned short* yb   = (unsigned short*)(ws + 50331648);            // 8 MB  [4096][1024]

  k_prep<<<dim3(5120), 256, 0, stream>>>(x, W_attn, W_proj, xb, wabt, wpbt);
  // QKV: M=4096, N=3072 -> 32x24 tiles = 768 blocks; XCD grid 4x2, region 8Mx12N
  // V third written transposed to vt directly (k_vt fused into epilogue).
  k_gemm<1><<<dim3(768), 512, 0, stream>>>(xb, wabt, b_attn, qkvb, vt, N3, CC, 8, 12, 2);
  k_attn<<<dim3(256), 512, 0, stream>>>(qkvb, vt, yb);
  // proj: M=4096, N=1024 -> 32x8 tiles = 256 blocks; XCD grid 8x1, region 4Mx8N
  k_gemm<0><<<dim3(256), 512, 0, stream>>>(yb, wpbt, b_proj, d_out, nullptr, CC, CC, 4, 8, 1);
}